// Round 1
// baseline (7634.628 us; speedup 1.0000x reference)
//
#include <hip/hip_runtime.h>
#include <hip/hip_bf16.h>

#define N_ROWS 8192
#define T_STEPS 60
#define HDIM 64
#define DFEAT 6

__device__ __forceinline__ float sigmoid_f(float x) {
    return 1.0f / (1.0f + __expf(-x));
}
__device__ __forceinline__ float tanh_f(float x) {
    float ax = fabsf(x);
    float t = __expf(-2.0f * ax);
    float r = (1.0f - t) / (1.0f + t);
    return copysignf(r, x);
}

// Fused 2-layer GRU over T=60 steps.
// Block: 1024 threads = 16 waves, 64 rows (lane = row), wave w owns hidden
// units j in [4w, 4w+4) for all 3 gates -> weight indices are wave-uniform
// (scalar loads). Hidden state in LDS, layout [k][row] (stride-1 across
// lanes, conflict-free), double buffered. 64 KiB LDS exactly.
__global__ __launch_bounds__(1024, 1)
void gru_fused(const float* __restrict__ x,
               const float* __restrict__ Wih0, const float* __restrict__ Whh0,
               const float* __restrict__ bih0, const float* __restrict__ bhh0,
               const float* __restrict__ Wih1, const float* __restrict__ Whh1,
               const float* __restrict__ bih1, const float* __restrict__ bhh1,
               float* __restrict__ hidden, float* __restrict__ colsum,
               float* __restrict__ colsumsq)
{
    __shared__ float h0[2][HDIM][64];
    __shared__ float h1[2][HDIM][64];

    const int lane = threadIdx.x & 63;
    const int wv   = threadIdx.x >> 6;    // 0..15
    const int jj0  = wv * 4;
    const int row_g = blockIdx.x * 64 + lane;
    const long xbase = (long)row_g * (DFEAT * T_STEPS);

    for (int i = threadIdx.x; i < 2 * HDIM * 64; i += 1024) {
        (&h0[0][0][0])[i] = 0.0f;
        (&h1[0][0][0])[i] = 0.0f;
    }

    // hoist biases (wave-uniform -> SGPRs)
    float br0[4], bz0[4], bxn0[4], bhn0[4];
    float br1[4], bz1[4], bxn1[4], bhn1[4];
#pragma unroll
    for (int q = 0; q < 4; ++q) {
        int j = jj0 + q;
        br0[q]  = bih0[j]       + bhh0[j];
        bz0[q]  = bih0[64 + j]  + bhh0[64 + j];
        bxn0[q] = bih0[128 + j];
        bhn0[q] = bhh0[128 + j];
        br1[q]  = bih1[j]       + bhh1[j];
        bz1[q]  = bih1[64 + j]  + bhh1[64 + j];
        bxn1[q] = bih1[128 + j];
        bhn1[q] = bhh1[128 + j];
    }
    __syncthreads();

#pragma unroll 1
    for (int t = 0; t < T_STEPS; ++t) {
        const int cur = t & 1, nxt = cur ^ 1;

        // ---------- layer 0 ----------
        float xv[DFEAT];
#pragma unroll
        for (int d = 0; d < DFEAT; ++d) xv[d] = x[xbase + d * T_STEPS + t];

        float ar[4], az[4], axn[4], ahn[4];
#pragma unroll
        for (int q = 0; q < 4; ++q) {
            int j = jj0 + q;
            float r = br0[q], z = bz0[q], xn = bxn0[q];
#pragma unroll
            for (int d = 0; d < DFEAT; ++d) {
                r  += xv[d] * Wih0[j * DFEAT + d];
                z  += xv[d] * Wih0[(64 + j) * DFEAT + d];
                xn += xv[d] * Wih0[(128 + j) * DFEAT + d];
            }
            ar[q] = r; az[q] = z; axn[q] = xn; ahn[q] = bhn0[q];
        }
#pragma unroll 4
        for (int k = 0; k < HDIM; ++k) {
            float hk = h0[cur][k][lane];
#pragma unroll
            for (int q = 0; q < 4; ++q) {
                int j = jj0 + q;
                ar[q]  += hk * Whh0[j * HDIM + k];
                az[q]  += hk * Whh0[(64 + j) * HDIM + k];
                ahn[q] += hk * Whh0[(128 + j) * HDIM + k];
            }
        }
#pragma unroll
        for (int q = 0; q < 4; ++q) {
            int j = jj0 + q;
            float r  = sigmoid_f(ar[q]);
            float z  = sigmoid_f(az[q]);
            float nn = tanh_f(axn[q] + r * ahn[q]);
            float hold = h0[cur][j][lane];
            h0[nxt][j][lane] = (1.0f - z) * nn + z * hold;
        }
        __syncthreads();   // layer-1 needs all of h0[nxt]

        // ---------- layer 1 ----------
#pragma unroll
        for (int q = 0; q < 4; ++q) {
            ar[q] = br1[q]; az[q] = bz1[q]; axn[q] = bxn1[q]; ahn[q] = bhn1[q];
        }
#pragma unroll 2
        for (int k = 0; k < HDIM; ++k) {
            float xk = h0[nxt][k][lane];
            float hk = h1[cur][k][lane];
#pragma unroll
            for (int q = 0; q < 4; ++q) {
                int j = jj0 + q;
                ar[q]  += xk * Wih1[j * HDIM + k]        + hk * Whh1[j * HDIM + k];
                az[q]  += xk * Wih1[(64 + j) * HDIM + k] + hk * Whh1[(64 + j) * HDIM + k];
                axn[q] += xk * Wih1[(128 + j) * HDIM + k];
                ahn[q] += hk * Whh1[(128 + j) * HDIM + k];
            }
        }
#pragma unroll
        for (int q = 0; q < 4; ++q) {
            int j = jj0 + q;
            float r  = sigmoid_f(ar[q]);
            float z  = sigmoid_f(az[q]);
            float nn = tanh_f(axn[q] + r * ahn[q]);
            float hold = h1[cur][j][lane];
            h1[nxt][j][lane] = (1.0f - z) * nn + z * hold;
        }
        __syncthreads();
    }

    // final hidden = h1[0] (written at t=59), plus BN1 column sums
#pragma unroll
    for (int q = 0; q < 4; ++q) {
        int j = jj0 + q;
        float v = h1[0][j][lane];
        hidden[(long)row_g * HDIM + j] = v;
        float sv = v, sq = v * v;
#pragma unroll
        for (int o = 32; o > 0; o >>= 1) {
            sv += __shfl_down(sv, o);
            sq += __shfl_down(sq, o);
        }
        if (lane == 0) {
            atomicAdd(&colsum[j], sv);
            atomicAdd(&colsumsq[j], sq);
        }
    }
}

__global__ void bn1_final(const float* __restrict__ colsum, const float* __restrict__ colsumsq,
                          const float* __restrict__ bnw, const float* __restrict__ bnb,
                          float* __restrict__ a1, float* __restrict__ c1)
{
    int j = threadIdx.x;
    float m = colsum[j] * (1.0f / N_ROWS);
    float v = colsumsq[j] * (1.0f / N_ROWS) - m * m;
    float a = bnw[j] * rsqrtf(v + 1e-5f);
    a1[j] = a;
    c1[j] = bnb[j] - m * a;
}

// G = hbn^T hbn (64x64), s[j] = sum_n e[n] hbn[n,j], e[n] = rowmean(hbn[n,:])
__global__ __launch_bounds__(256)
void stats_kernel(const float* __restrict__ hidden, const float* __restrict__ a1,
                  const float* __restrict__ c1, float* __restrict__ G,
                  float* __restrict__ s, float* __restrict__ e)
{
    __shared__ float tile[128][65];
    __shared__ float el[128];
    const int b = blockIdx.x, tid = threadIdx.x;
    for (int i = tid; i < 128 * 64; i += 256) {
        int r = i >> 6, j = i & 63;
        tile[r][j] = hidden[(long)(b * 128 + r) * 64 + j] * a1[j] + c1[j];
    }
    __syncthreads();
    for (int r = tid; r < 128; r += 256) {
        float sum = 0.0f;
        for (int j = 0; j < 64; ++j) sum += tile[r][j];
        float ev = sum * (1.0f / 64.0f);
        el[r] = ev;
        e[b * 128 + r] = ev;
    }
    __syncthreads();
    const int j = tid & 63, kg = tid >> 6;
    float acc[16];
#pragma unroll
    for (int q = 0; q < 16; ++q) acc[q] = 0.0f;
    for (int r = 0; r < 128; ++r) {
        float hj = tile[r][j];
#pragma unroll
        for (int q = 0; q < 16; ++q) acc[q] += tile[r][kg * 16 + q] * hj;
    }
#pragma unroll
    for (int q = 0; q < 16; ++q) atomicAdd(&G[(kg * 16 + q) * 64 + j], acc[q]);
    if (tid < 64) {
        float svv = 0.0f;
        for (int r = 0; r < 128; ++r) svv += el[r] * tile[r][tid];
        atomicAdd(&s[tid], svv);
    }
}

// M[k][p] = (1/64) sum_j G[k][j] fc_w[p][j];  sv[p] = sum_j s[j] fc_w[p][j]
__global__ void prep_M(const float* __restrict__ G, const float* __restrict__ s,
                       const float* __restrict__ fcw, float* __restrict__ M,
                       float* __restrict__ sv)
{
    int tid = threadIdx.x;
    for (int i = tid; i < 4096; i += 256) {
        int k = i >> 6, p = i & 63;
        float acc = 0.0f;
        for (int j = 0; j < 64; ++j) acc += G[k * 64 + j] * fcw[p * 64 + j];
        M[i] = acc * (1.0f / 64.0f);
    }
    if (tid < 64) {
        float acc = 0.0f;
        for (int j = 0; j < 64; ++j) acc += s[j] * fcw[tid * 64 + j];
        sv[tid] = acc;
    }
}

// out2[n,p] = hbn[n,:].M[:,p] - e[n]*sv[p] + fc_b[p]
__global__ __launch_bounds__(256)
void out2_kernel(const float* __restrict__ hidden, const float* __restrict__ a1,
                 const float* __restrict__ c1, const float* __restrict__ M,
                 const float* __restrict__ sv, const float* __restrict__ fcb,
                 const float* __restrict__ e, float* __restrict__ out2)
{
    __shared__ float tile[128][65];
    __shared__ float Ms[64][65];
    const int b = blockIdx.x, tid = threadIdx.x;
    for (int i = tid; i < 128 * 64; i += 256) {
        int r = i >> 6, j = i & 63;
        tile[r][j] = hidden[(long)(b * 128 + r) * 64 + j] * a1[j] + c1[j];
    }
    for (int i = tid; i < 4096; i += 256) Ms[i >> 6][i & 63] = M[i];
    __syncthreads();
    const int r = tid & 127, ph = tid >> 7;
    const float ev = e[b * 128 + r];
#pragma unroll 1
    for (int pp = 0; pp < 32; ++pp) {
        int p = ph * 32 + pp;
        float acc = 0.0f;
#pragma unroll 8
        for (int k = 0; k < 64; ++k) acc += tile[r][k] * Ms[k][p];
        out2[(long)(b * 128 + r) * 64 + p] = acc - ev * sv[p] + fcb[p];
    }
}

// per-feature mean/var over N of out2 -> a2, c2  (one block per feature)
__global__ __launch_bounds__(256)
void bn2_stats(const float* __restrict__ out2, const float* __restrict__ bnw,
               const float* __restrict__ bnb, float* __restrict__ a2,
               float* __restrict__ c2)
{
    const int p = blockIdx.x, tid = threadIdx.x;
    float sum = 0.0f, sumsq = 0.0f;
    for (int n = tid; n < N_ROWS; n += 256) {
        float v = out2[(long)n * 64 + p];
        sum += v; sumsq += v * v;
    }
    __shared__ float rs[256], rq[256];
    rs[tid] = sum; rq[tid] = sumsq;
    __syncthreads();
    for (int o = 128; o > 0; o >>= 1) {
        if (tid < o) { rs[tid] += rs[tid + o]; rq[tid] += rq[tid + o]; }
        __syncthreads();
    }
    if (tid == 0) {
        float m = rs[0] * (1.0f / N_ROWS);
        float v = rq[0] * (1.0f / N_ROWS) - m * m;
        float a = bnw[p] * rsqrtf(v + 1e-5f);
        a2[p] = a;
        c2[p] = bnb[p] - m * a;
    }
}

// y[n] = sum_p lrelu(out2[n,p]*a2[p]+c2[p]) * wout[p] + bout
__global__ __launch_bounds__(256)
void final_kernel(const float* __restrict__ out2, const float* __restrict__ a2,
                  const float* __restrict__ c2, const float* __restrict__ wout,
                  const float* __restrict__ bout, float* __restrict__ y)
{
    const int n = blockIdx.x * 256 + threadIdx.x;
    float acc = bout[0];
#pragma unroll 8
    for (int p = 0; p < 64; ++p) {
        float v = out2[(long)n * 64 + p] * a2[p] + c2[p];
        v = (v >= 0.0f) ? v : 0.01f * v;
        acc += v * wout[p];
    }
    y[n] = acc;
}

extern "C" void kernel_launch(void* const* d_in, const int* in_sizes, int n_in,
                              void* d_out, int out_size, void* d_ws, size_t ws_size,
                              hipStream_t stream)
{
    const float* x    = (const float*)d_in[0];
    const float* Wih0 = (const float*)d_in[1];
    const float* Whh0 = (const float*)d_in[2];
    const float* bih0 = (const float*)d_in[3];
    const float* bhh0 = (const float*)d_in[4];
    const float* Wih1 = (const float*)d_in[5];
    const float* Whh1 = (const float*)d_in[6];
    const float* bih1 = (const float*)d_in[7];
    const float* bhh1 = (const float*)d_in[8];
    const float* bn1w = (const float*)d_in[9];
    const float* bn1b = (const float*)d_in[10];
    const float* fcw  = (const float*)d_in[11];
    const float* fcb  = (const float*)d_in[12];
    const float* bn2w = (const float*)d_in[13];
    const float* bn2b = (const float*)d_in[14];
    const float* fow  = (const float*)d_in[15];
    const float* fob  = (const float*)d_in[16];
    float* y = (float*)d_out;

    float* ws = (float*)d_ws;
    float* hidden = ws;                  // 8192*64
    float* out2   = ws + 524288;         // 8192*64
    float* sm     = ws + 1048576;        // small block
    float* colsum   = sm;                // 64   } zeroed
    float* colsumsq = sm + 64;           // 64   } zeroed
    float* G        = sm + 128;          // 4096 } zeroed
    float* s        = sm + 4224;         // 64   } zeroed
    float* a1       = sm + 4288;         // 64
    float* c1       = sm + 4352;         // 64
    float* M        = sm + 4416;         // 4096
    float* sv       = sm + 8512;         // 64
    float* a2       = sm + 8576;         // 64
    float* c2       = sm + 8640;         // 64
    float* e        = sm + 8704;         // 8192

    hipMemsetAsync(colsum, 0, (64 + 64 + 4096 + 64) * sizeof(float), stream);

    gru_fused<<<128, 1024, 0, stream>>>(x, Wih0, Whh0, bih0, bhh0,
                                        Wih1, Whh1, bih1, bhh1,
                                        hidden, colsum, colsumsq);
    bn1_final<<<1, 64, 0, stream>>>(colsum, colsumsq, bn1w, bn1b, a1, c1);
    stats_kernel<<<64, 256, 0, stream>>>(hidden, a1, c1, G, s, e);
    prep_M<<<1, 256, 0, stream>>>(G, s, fcw, M, sv);
    out2_kernel<<<64, 256, 0, stream>>>(hidden, a1, c1, M, sv, fcb, e, out2);
    bn2_stats<<<64, 256, 0, stream>>>(out2, bn2w, bn2b, a2, c2);
    final_kernel<<<32, 256, 0, stream>>>(out2, a2, c2, fow, fob, y);
}

// Round 2
// 561.932 us; speedup vs baseline: 13.5864x; 13.5864x over previous
//
#include <hip/hip_runtime.h>
#include <hip/hip_bf16.h>

#define N_ROWS 8192
#define T_STEPS 60
#define HDIM 64
#define DFEAT 6

typedef short bf16x8 __attribute__((ext_vector_type(8)));
typedef float f32x4 __attribute__((ext_vector_type(4)));
typedef float fvec4 __attribute__((ext_vector_type(4)));

__device__ __forceinline__ float sigmoid_f(float x) {
    return 1.0f / (1.0f + __expf(-x));
}
__device__ __forceinline__ float tanh_f(float x) {
    float ax = fabsf(x);
    float t = __expf(-2.0f * ax);
    float r = (1.0f - t) / (1.0f + t);
    return copysignf(r, x);
}
__device__ __forceinline__ unsigned short bf16_rn(float x) {
    unsigned u = __float_as_uint(x);
    return (unsigned short)((u + 0x7FFFu + ((u >> 16) & 1u)) >> 16);
}
__device__ __forceinline__ float bf16f(unsigned short h) {
    return __uint_as_float(((unsigned)h) << 16);
}

#define MFMA16(a, b, c) __builtin_amdgcn_mfma_f32_16x16x32_bf16(a, b, c, 0, 0, 0)

// Load 8 consecutive fp32 weights W[(g*64+jcol)][kf*32+rowgrp*8 .. +8)
// and split into hi/lo bf16 fragments (B-frag layout: col=lane&15, k=(lane>>4)*8+e).
#define LOAD_SPLIT(W, g, kf, HI, LO) do {                                     \
    const float* _p = (W) + ((g)*64 + jcol)*64 + (kf)*32 + rowgrp*8;          \
    fvec4 _v0 = *(const fvec4*)_p;                                            \
    fvec4 _v1 = *(const fvec4*)(_p + 4);                                      \
    bf16x8 _hi, _lo;                                                          \
    _Pragma("unroll")                                                         \
    for (int _e = 0; _e < 4; ++_e) {                                          \
        unsigned short _h0 = bf16_rn(_v0[_e]);                                \
        _hi[_e] = (short)_h0;                                                 \
        _lo[_e] = (short)bf16_rn(_v0[_e] - bf16f(_h0));                       \
        unsigned short _h1 = bf16_rn(_v1[_e]);                                \
        _hi[4 + _e] = (short)_h1;                                             \
        _lo[4 + _e] = (short)bf16_rn(_v1[_e] - bf16f(_h1));                   \
    }                                                                         \
    HI = _hi; LO = _lo;                                                       \
} while (0)

// Persistent MFMA GRU. 512 blocks x 256 threads (4 waves).
// Block owns 16 rows; wave wv owns output columns [16*wv, 16*wv+16).
// Weights live in VGPRs as split-bf16 B-fragments (loaded once).
// h bounces through LDS (bf16 hi+lo planes, row stride 72 for bank spread).
__global__ __launch_bounds__(256, 2)
void gru_fused(const float* __restrict__ x,
               const float* __restrict__ Wih0, const float* __restrict__ Whh0,
               const float* __restrict__ bih0, const float* __restrict__ bhh0,
               const float* __restrict__ Wih1, const float* __restrict__ Whh1,
               const float* __restrict__ bih1, const float* __restrict__ bhh1,
               float* __restrict__ hidden, float* __restrict__ colsum,
               float* __restrict__ colsumsq)
{
    __shared__ __align__(16) short h0_hi[16][72];
    __shared__ __align__(16) short h0_lo[16][72];
    __shared__ __align__(16) short h1_hi[16][72];
    __shared__ __align__(16) short h1_lo[16][72];
    __shared__ float xs[16][360];

    const int tid = threadIdx.x;
    const int lane = tid & 63;
    const int wv = tid >> 6;          // 0..3
    const int lrow = lane & 15;       // A-frag row / C col
    const int rowgrp = lane >> 4;     // 0..3
    const int jcol = wv * 16 + lrow;  // this lane's output column (0..63)
    const int rbase = blockIdx.x * 16;

    for (int i = tid; i < 16 * 72; i += 256) {
        ((short*)h0_hi)[i] = 0; ((short*)h0_lo)[i] = 0;
        ((short*)h1_hi)[i] = 0; ((short*)h1_lo)[i] = 0;
    }
    for (int r = 0; r < 16; ++r)
        for (int c = tid; c < 360; c += 256)
            xs[r][c] = x[(long)(rbase + r) * 360 + c];

    // ---- weight fragments in registers (once) ----
    bf16x8 w0hi[3][2], w0lo[3][2];   // Whh0
    bf16x8 wxhi[3][2], wxlo[3][2];   // Wih1
    bf16x8 whhi[3][2], whlo[3][2];   // Whh1
#pragma unroll
    for (int g = 0; g < 3; ++g) {
#pragma unroll
        for (int kf = 0; kf < 2; ++kf) {
            LOAD_SPLIT(Whh0, g, kf, w0hi[g][kf], w0lo[g][kf]);
            LOAD_SPLIT(Wih1, g, kf, wxhi[g][kf], wxlo[g][kf]);
            LOAD_SPLIT(Whh1, g, kf, whhi[g][kf], whlo[g][kf]);
        }
    }
    // layer-0 input weights (K=6, done on VALU) + biases
    float wir[6], wiz[6], win[6];
#pragma unroll
    for (int d = 0; d < 6; ++d) {
        wir[d] = Wih0[jcol * 6 + d];
        wiz[d] = Wih0[(64 + jcol) * 6 + d];
        win[d] = Wih0[(128 + jcol) * 6 + d];
    }
    const float br0  = bih0[jcol] + bhh0[jcol];
    const float bz0  = bih0[64 + jcol] + bhh0[64 + jcol];
    const float bxn0 = bih0[128 + jcol];
    const float bhn0 = bhh0[128 + jcol];
    const float br1  = bih1[jcol] + bhh1[jcol];
    const float bz1  = bih1[64 + jcol] + bhh1[64 + jcol];
    const float bxn1 = bih1[128 + jcol];
    const float bhn1 = bhh1[128 + jcol];

    float h0reg[4] = {0.f, 0.f, 0.f, 0.f};
    float h1reg[4] = {0.f, 0.f, 0.f, 0.f};
    __syncthreads();

    for (int t = 0; t < T_STEPS; ++t) {
        // ================= layer 0 =================
        bf16x8 ahi[2], alo[2];
#pragma unroll
        for (int kf = 0; kf < 2; ++kf) {
            ahi[kf] = *(const bf16x8*)&h0_hi[lrow][kf * 32 + rowgrp * 8];
            alo[kf] = *(const bf16x8*)&h0_lo[lrow][kf * 32 + rowgrp * 8];
        }
        f32x4 accr, accz, acchn;
        float xnv[4];
#pragma unroll
        for (int q = 0; q < 4; ++q) {
            float xr = br0, xz = bz0, xn = bxn0;
#pragma unroll
            for (int d = 0; d < 6; ++d) {
                float xvv = xs[rowgrp * 4 + q][d * 60 + t];
                xr += xvv * wir[d];
                xz += xvv * wiz[d];
                xn += xvv * win[d];
            }
            accr[q] = xr; accz[q] = xz; xnv[q] = xn; acchn[q] = bhn0;
        }
#pragma unroll
        for (int kf = 0; kf < 2; ++kf) {
            accr  = MFMA16(ahi[kf], w0hi[0][kf], accr);
            accr  = MFMA16(ahi[kf], w0lo[0][kf], accr);
            accr  = MFMA16(alo[kf], w0hi[0][kf], accr);
            accz  = MFMA16(ahi[kf], w0hi[1][kf], accz);
            accz  = MFMA16(ahi[kf], w0lo[1][kf], accz);
            accz  = MFMA16(alo[kf], w0hi[1][kf], accz);
            acchn = MFMA16(ahi[kf], w0hi[2][kf], acchn);
            acchn = MFMA16(ahi[kf], w0lo[2][kf], acchn);
            acchn = MFMA16(alo[kf], w0hi[2][kf], acchn);
        }
#pragma unroll
        for (int q = 0; q < 4; ++q) {
            float r = sigmoid_f(accr[q]);
            float z = sigmoid_f(accz[q]);
            float n = tanh_f(xnv[q] + r * acchn[q]);
            h0reg[q] = (1.0f - z) * n + z * h0reg[q];
        }
        __syncthreads();   // (1) all reads of old h0 done
#pragma unroll
        for (int q = 0; q < 4; ++q) {
            float v = h0reg[q];
            unsigned short hb = bf16_rn(v);
            h0_hi[rowgrp * 4 + q][jcol] = (short)hb;
            h0_lo[rowgrp * 4 + q][jcol] = (short)bf16_rn(v - bf16f(hb));
        }
        __syncthreads();   // (2) new h0 visible

        // ================= layer 1 =================
        bf16x8 xfhi[2], xflo[2], hfhi[2], hflo[2];
#pragma unroll
        for (int kf = 0; kf < 2; ++kf) {
            xfhi[kf] = *(const bf16x8*)&h0_hi[lrow][kf * 32 + rowgrp * 8];
            xflo[kf] = *(const bf16x8*)&h0_lo[lrow][kf * 32 + rowgrp * 8];
            hfhi[kf] = *(const bf16x8*)&h1_hi[lrow][kf * 32 + rowgrp * 8];
            hflo[kf] = *(const bf16x8*)&h1_lo[lrow][kf * 32 + rowgrp * 8];
        }
        f32x4 accr1  = {br1, br1, br1, br1};
        f32x4 accz1  = {bz1, bz1, bz1, bz1};
        f32x4 accxn  = {bxn1, bxn1, bxn1, bxn1};
        f32x4 acchn1 = {bhn1, bhn1, bhn1, bhn1};
#pragma unroll
        for (int kf = 0; kf < 2; ++kf) {
            accr1  = MFMA16(xfhi[kf], wxhi[0][kf], accr1);
            accr1  = MFMA16(xfhi[kf], wxlo[0][kf], accr1);
            accr1  = MFMA16(xflo[kf], wxhi[0][kf], accr1);
            accr1  = MFMA16(hfhi[kf], whhi[0][kf], accr1);
            accr1  = MFMA16(hfhi[kf], whlo[0][kf], accr1);
            accr1  = MFMA16(hflo[kf], whhi[0][kf], accr1);

            accz1  = MFMA16(xfhi[kf], wxhi[1][kf], accz1);
            accz1  = MFMA16(xfhi[kf], wxlo[1][kf], accz1);
            accz1  = MFMA16(xflo[kf], wxhi[1][kf], accz1);
            accz1  = MFMA16(hfhi[kf], whhi[1][kf], accz1);
            accz1  = MFMA16(hfhi[kf], whlo[1][kf], accz1);
            accz1  = MFMA16(hflo[kf], whhi[1][kf], accz1);

            accxn  = MFMA16(xfhi[kf], wxhi[2][kf], accxn);
            accxn  = MFMA16(xfhi[kf], wxlo[2][kf], accxn);
            accxn  = MFMA16(xflo[kf], wxhi[2][kf], accxn);

            acchn1 = MFMA16(hfhi[kf], whhi[2][kf], acchn1);
            acchn1 = MFMA16(hfhi[kf], whlo[2][kf], acchn1);
            acchn1 = MFMA16(hflo[kf], whhi[2][kf], acchn1);
        }
#pragma unroll
        for (int q = 0; q < 4; ++q) {
            float r = sigmoid_f(accr1[q]);
            float z = sigmoid_f(accz1[q]);
            float n = tanh_f(accxn[q] + r * acchn1[q]);
            h1reg[q] = (1.0f - z) * n + z * h1reg[q];
        }
        __syncthreads();   // (3) all reads of old h1 + new h0 done
#pragma unroll
        for (int q = 0; q < 4; ++q) {
            float v = h1reg[q];
            unsigned short hb = bf16_rn(v);
            h1_hi[rowgrp * 4 + q][jcol] = (short)hb;
            h1_lo[rowgrp * 4 + q][jcol] = (short)bf16_rn(v - bf16f(hb));
        }
    }

    // epilogue: final hidden + BN1 column sums
#pragma unroll
    for (int q = 0; q < 4; ++q)
        hidden[(long)(rbase + rowgrp * 4 + q) * 64 + jcol] = h1reg[q];

    float sv_ = 0.f, sq_ = 0.f;
#pragma unroll
    for (int q = 0; q < 4; ++q) { sv_ += h1reg[q]; sq_ += h1reg[q] * h1reg[q]; }
    sv_ += __shfl_xor(sv_, 16); sq_ += __shfl_xor(sq_, 16);
    sv_ += __shfl_xor(sv_, 32); sq_ += __shfl_xor(sq_, 32);
    if (rowgrp == 0) {
        atomicAdd(&colsum[jcol], sv_);
        atomicAdd(&colsumsq[jcol], sq_);
    }
}

__global__ void bn1_final(const float* __restrict__ colsum, const float* __restrict__ colsumsq,
                          const float* __restrict__ bnw, const float* __restrict__ bnb,
                          float* __restrict__ a1, float* __restrict__ c1)
{
    int j = threadIdx.x;
    float m = colsum[j] * (1.0f / N_ROWS);
    float v = colsumsq[j] * (1.0f / N_ROWS) - m * m;
    float a = bnw[j] * rsqrtf(v + 1e-5f);
    a1[j] = a;
    c1[j] = bnb[j] - m * a;
}

// G = hbn^T hbn (64x64), s[j] = sum_n e[n] hbn[n,j], e[n] = rowmean(hbn[n,:])
__global__ __launch_bounds__(256)
void stats_kernel(const float* __restrict__ hidden, const float* __restrict__ a1,
                  const float* __restrict__ c1, float* __restrict__ G,
                  float* __restrict__ s, float* __restrict__ e)
{
    __shared__ float tile[128][65];
    __shared__ float el[128];
    const int b = blockIdx.x, tid = threadIdx.x;
    for (int i = tid; i < 128 * 64; i += 256) {
        int r = i >> 6, j = i & 63;
        tile[r][j] = hidden[(long)(b * 128 + r) * 64 + j] * a1[j] + c1[j];
    }
    __syncthreads();
    for (int r = tid; r < 128; r += 256) {
        float sum = 0.0f;
        for (int j = 0; j < 64; ++j) sum += tile[r][j];
        float ev = sum * (1.0f / 64.0f);
        el[r] = ev;
        e[b * 128 + r] = ev;
    }
    __syncthreads();
    const int j = tid & 63, kg = tid >> 6;
    float acc[16];
#pragma unroll
    for (int q = 0; q < 16; ++q) acc[q] = 0.0f;
    for (int r = 0; r < 128; ++r) {
        float hj = tile[r][j];
#pragma unroll
        for (int q = 0; q < 16; ++q) acc[q] += tile[r][kg * 16 + q] * hj;
    }
#pragma unroll
    for (int q = 0; q < 16; ++q) atomicAdd(&G[(kg * 16 + q) * 64 + j], acc[q]);
    if (tid < 64) {
        float svv = 0.0f;
        for (int r = 0; r < 128; ++r) svv += el[r] * tile[r][tid];
        atomicAdd(&s[tid], svv);
    }
}

// M[k][p] = (1/64) sum_j G[k][j] fc_w[p][j];  sv[p] = sum_j s[j] fc_w[p][j]
__global__ void prep_M(const float* __restrict__ G, const float* __restrict__ s,
                       const float* __restrict__ fcw, float* __restrict__ M,
                       float* __restrict__ sv)
{
    int tid = threadIdx.x;
    for (int i = tid; i < 4096; i += 256) {
        int k = i >> 6, p = i & 63;
        float acc = 0.0f;
        for (int j = 0; j < 64; ++j) acc += G[k * 64 + j] * fcw[p * 64 + j];
        M[i] = acc * (1.0f / 64.0f);
    }
    if (tid < 64) {
        float acc = 0.0f;
        for (int j = 0; j < 64; ++j) acc += s[j] * fcw[tid * 64 + j];
        sv[tid] = acc;
    }
}

// out2[n,p] = hbn[n,:].M[:,p] - e[n]*sv[p] + fc_b[p]
__global__ __launch_bounds__(256)
void out2_kernel(const float* __restrict__ hidden, const float* __restrict__ a1,
                 const float* __restrict__ c1, const float* __restrict__ M,
                 const float* __restrict__ sv, const float* __restrict__ fcb,
                 const float* __restrict__ e, float* __restrict__ out2)
{
    __shared__ float tile[128][65];
    __shared__ float Ms[64][65];
    const int b = blockIdx.x, tid = threadIdx.x;
    for (int i = tid; i < 128 * 64; i += 256) {
        int r = i >> 6, j = i & 63;
        tile[r][j] = hidden[(long)(b * 128 + r) * 64 + j] * a1[j] + c1[j];
    }
    for (int i = tid; i < 4096; i += 256) Ms[i >> 6][i & 63] = M[i];
    __syncthreads();
    const int r = tid & 127, ph = tid >> 7;
    const float ev = e[b * 128 + r];
#pragma unroll 1
    for (int pp = 0; pp < 32; ++pp) {
        int p = ph * 32 + pp;
        float acc = 0.0f;
#pragma unroll 8
        for (int k = 0; k < 64; ++k) acc += tile[r][k] * Ms[k][p];
        out2[(long)(b * 128 + r) * 64 + p] = acc - ev * sv[p] + fcb[p];
    }
}

// per-feature mean/var over N of out2 -> a2, c2  (one block per feature)
__global__ __launch_bounds__(256)
void bn2_stats(const float* __restrict__ out2, const float* __restrict__ bnw,
               const float* __restrict__ bnb, float* __restrict__ a2,
               float* __restrict__ c2)
{
    const int p = blockIdx.x, tid = threadIdx.x;
    float sum = 0.0f, sumsq = 0.0f;
    for (int n = tid; n < N_ROWS; n += 256) {
        float v = out2[(long)n * 64 + p];
        sum += v; sumsq += v * v;
    }
    __shared__ float rs[256], rq[256];
    rs[tid] = sum; rq[tid] = sumsq;
    __syncthreads();
    for (int o = 128; o > 0; o >>= 1) {
        if (tid < o) { rs[tid] += rs[tid + o]; rq[tid] += rq[tid + o]; }
        __syncthreads();
    }
    if (tid == 0) {
        float m = rs[0] * (1.0f / N_ROWS);
        float v = rq[0] * (1.0f / N_ROWS) - m * m;
        float a = bnw[p] * rsqrtf(v + 1e-5f);
        a2[p] = a;
        c2[p] = bnb[p] - m * a;
    }
}

// y[n] = sum_p lrelu(out2[n,p]*a2[p]+c2[p]) * wout[p] + bout
__global__ __launch_bounds__(256)
void final_kernel(const float* __restrict__ out2, const float* __restrict__ a2,
                  const float* __restrict__ c2, const float* __restrict__ wout,
                  const float* __restrict__ bout, float* __restrict__ y)
{
    const int n = blockIdx.x * 256 + threadIdx.x;
    float acc = bout[0];
#pragma unroll 8
    for (int p = 0; p < 64; ++p) {
        float v = out2[(long)n * 64 + p] * a2[p] + c2[p];
        v = (v >= 0.0f) ? v : 0.01f * v;
        acc += v * wout[p];
    }
    y[n] = acc;
}

extern "C" void kernel_launch(void* const* d_in, const int* in_sizes, int n_in,
                              void* d_out, int out_size, void* d_ws, size_t ws_size,
                              hipStream_t stream)
{
    const float* x    = (const float*)d_in[0];
    const float* Wih0 = (const float*)d_in[1];
    const float* Whh0 = (const float*)d_in[2];
    const float* bih0 = (const float*)d_in[3];
    const float* bhh0 = (const float*)d_in[4];
    const float* Wih1 = (const float*)d_in[5];
    const float* Whh1 = (const float*)d_in[6];
    const float* bih1 = (const float*)d_in[7];
    const float* bhh1 = (const float*)d_in[8];
    const float* bn1w = (const float*)d_in[9];
    const float* bn1b = (const float*)d_in[10];
    const float* fcw  = (const float*)d_in[11];
    const float* fcb  = (const float*)d_in[12];
    const float* bn2w = (const float*)d_in[13];
    const float* bn2b = (const float*)d_in[14];
    const float* fow  = (const float*)d_in[15];
    const float* fob  = (const float*)d_in[16];
    float* y = (float*)d_out;

    float* ws = (float*)d_ws;
    float* hidden = ws;                  // 8192*64
    float* out2   = ws + 524288;         // 8192*64
    float* sm     = ws + 1048576;        // small block
    float* colsum   = sm;                // 64   } zeroed
    float* colsumsq = sm + 64;           // 64   } zeroed
    float* G        = sm + 128;          // 4096 } zeroed
    float* s        = sm + 4224;         // 64   } zeroed
    float* a1       = sm + 4288;         // 64
    float* c1       = sm + 4352;         // 64
    float* M        = sm + 4416;         // 4096
    float* sv       = sm + 8512;         // 64
    float* a2       = sm + 8576;         // 64
    float* c2       = sm + 8640;         // 64
    float* e        = sm + 8704;         // 8192

    hipMemsetAsync(colsum, 0, (64 + 64 + 4096 + 64) * sizeof(float), stream);

    gru_fused<<<512, 256, 0, stream>>>(x, Wih0, Whh0, bih0, bhh0,
                                       Wih1, Whh1, bih1, bhh1,
                                       hidden, colsum, colsumsq);
    bn1_final<<<1, 64, 0, stream>>>(colsum, colsumsq, bn1w, bn1b, a1, c1);
    stats_kernel<<<64, 256, 0, stream>>>(hidden, a1, c1, G, s, e);
    prep_M<<<1, 256, 0, stream>>>(G, s, fcw, M, sv);
    out2_kernel<<<64, 256, 0, stream>>>(hidden, a1, c1, M, sv, fcb, e, out2);
    bn2_stats<<<64, 256, 0, stream>>>(out2, bn2w, bn2b, a2, c2);
    final_kernel<<<32, 256, 0, stream>>>(out2, a2, c2, fow, fob, y);
}

// Round 3
// 462.427 us; speedup vs baseline: 16.5099x; 1.2152x over previous
//
#include <hip/hip_runtime.h>
#include <hip/hip_bf16.h>

#define N_ROWS 8192
#define T_STEPS 60
#define HDIM 64
#define DFEAT 6

typedef short bf16x8 __attribute__((ext_vector_type(8)));
typedef float f32x4 __attribute__((ext_vector_type(4)));
typedef float fvec4 __attribute__((ext_vector_type(4)));

__device__ __forceinline__ float sigmoid_f(float x) {
    return 1.0f / (1.0f + __expf(-x));
}
__device__ __forceinline__ float tanh_f(float x) {
    float ax = fabsf(x);
    float t = __expf(-2.0f * ax);
    float r = (1.0f - t) / (1.0f + t);
    return copysignf(r, x);
}
__device__ __forceinline__ unsigned short bf16_rn(float x) {
    unsigned u = __float_as_uint(x);
    return (unsigned short)((u + 0x7FFFu + ((u >> 16) & 1u)) >> 16);
}
__device__ __forceinline__ float bf16f(unsigned short h) {
    return __uint_as_float(((unsigned)h) << 16);
}

#define MFMA16(a, b, c) __builtin_amdgcn_mfma_f32_16x16x32_bf16(a, b, c, 0, 0, 0)

// Load 8 consecutive fp32 weights W[(g*64+jcol)][kf*32+rowgrp*8 .. +8)
// split into hi/lo bf16 B-fragments (col=lane&15, k=(lane>>4)*8+e).
#define LOAD_SPLIT(W, g, kf, HI, LO) do {                                     \
    const float* _p = (W) + ((g)*64 + jcol)*64 + (kf)*32 + rowgrp*8;          \
    fvec4 _v0 = *(const fvec4*)_p;                                            \
    fvec4 _v1 = *(const fvec4*)(_p + 4);                                      \
    bf16x8 _hi, _lo;                                                          \
    _Pragma("unroll")                                                         \
    for (int _e = 0; _e < 4; ++_e) {                                          \
        unsigned short _h0 = bf16_rn(_v0[_e]);                                \
        _hi[_e] = (short)_h0;                                                 \
        _lo[_e] = (short)bf16_rn(_v0[_e] - bf16f(_h0));                       \
        unsigned short _h1 = bf16_rn(_v1[_e]);                                \
        _hi[4 + _e] = (short)_h1;                                             \
        _lo[4 + _e] = (short)bf16_rn(_v1[_e] - bf16f(_h1));                   \
    }                                                                         \
    HI = _hi; LO = _lo;                                                       \
} while (0)

// swizzled LDS index for h planes: element (row, col) -> row*64 + (col ^ ((row&7)<<3))
__device__ __forceinline__ int hswz(int row, int col) {
    return row * 64 + (col ^ ((row & 7) << 3));
}

// Persistent MFMA GRU. 512 blocks x 256 threads (4 waves).
// Block owns 16 rows; wave wv owns output columns [16*wv, 16*wv+16).
// Weights in registers as split-bf16 B-fragments. x pre-staged as per-step
// MFMA A-fragments in LDS. h planes double-buffered, XOR-swizzled.
// 2 barriers per timestep.
__global__ __launch_bounds__(256, 2)
void gru_fused(const float* __restrict__ x,
               const float* __restrict__ Wih0, const float* __restrict__ Whh0,
               const float* __restrict__ bih0, const float* __restrict__ bhh0,
               const float* __restrict__ Wih1, const float* __restrict__ Whh1,
               const float* __restrict__ bih1, const float* __restrict__ bhh1,
               float* __restrict__ hidden, float* __restrict__ colsum,
               float* __restrict__ colsumsq)
{
    __shared__ __align__(16) short h0s[2][2][1024];   // [buf][hi/lo][swizzled 16x64]
    __shared__ __align__(16) short h1s[2][2][1024];
    __shared__ __align__(16) short xhi[T_STEPS][16][8];  // per-step x A-frags
    __shared__ __align__(16) short xlo[T_STEPS][16][8];

    const int tid = threadIdx.x;
    const int lane = tid & 63;
    const int wv = tid >> 6;          // 0..3
    const int lrow = lane & 15;       // A row / C col-within-tile
    const int rowgrp = lane >> 4;     // 0..3
    const int jcol = wv * 16 + lrow;  // this lane's output column (0..63)
    const int rbase = blockIdx.x * 16;

    // zero h planes
    for (int i = tid; i < 2 * 2 * 1024; i += 256) {
        (&h0s[0][0][0])[i] = 0;
        (&h1s[0][0][0])[i] = 0;
    }
    // stage x -> per-step A-fragments (hi/lo)
    for (int idx = tid; idx < 16 * T_STEPS; idx += 256) {
        int t = idx >> 4, r = idx & 15;
        const float* xp = x + (long)(rbase + r) * (DFEAT * T_STEPS) + t;
        bf16x8 hi, lo;
#pragma unroll
        for (int d = 0; d < DFEAT; ++d) {
            float v = xp[d * T_STEPS];
            unsigned short hb = bf16_rn(v);
            hi[d] = (short)hb;
            lo[d] = (short)bf16_rn(v - bf16f(hb));
        }
        hi[6] = 0; hi[7] = 0; lo[6] = 0; lo[7] = 0;
        *(bf16x8*)&xhi[t][r][0] = hi;
        *(bf16x8*)&xlo[t][r][0] = lo;
    }

    // ---- weight fragments in registers (once) ----
    bf16x8 w0hi[3][2], w0lo[3][2];   // Whh0
    bf16x8 wxhi[3][2], wxlo[3][2];   // Wih1
    bf16x8 whhi[3][2], whlo[3][2];   // Whh1
#pragma unroll
    for (int g = 0; g < 3; ++g) {
#pragma unroll
        for (int kf = 0; kf < 2; ++kf) {
            LOAD_SPLIT(Whh0, g, kf, w0hi[g][kf], w0lo[g][kf]);
            LOAD_SPLIT(Wih1, g, kf, wxhi[g][kf], wxlo[g][kf]);
            LOAD_SPLIT(Whh1, g, kf, whhi[g][kf], whlo[g][kf]);
        }
    }
    // x-part B-fragments (K=6 zero-padded, only rowgrp 0 lanes carry data)
    bf16x8 wxbhi[3], wxblo[3];
#pragma unroll
    for (int g = 0; g < 3; ++g) {
        bf16x8 hi = {0,0,0,0,0,0,0,0}, lo = {0,0,0,0,0,0,0,0};
        if (rowgrp == 0) {
#pragma unroll
            for (int e = 0; e < DFEAT; ++e) {
                float v = Wih0[(g * 64 + jcol) * DFEAT + e];
                unsigned short hb = bf16_rn(v);
                hi[e] = (short)hb;
                lo[e] = (short)bf16_rn(v - bf16f(hb));
            }
        }
        wxbhi[g] = hi; wxblo[g] = lo;
    }

    const float br0  = bih0[jcol] + bhh0[jcol];
    const float bz0  = bih0[64 + jcol] + bhh0[64 + jcol];
    const float bxn0 = bih0[128 + jcol];
    const float bhn0 = bhh0[128 + jcol];
    const float br1  = bih1[jcol] + bhh1[jcol];
    const float bz1  = bih1[64 + jcol] + bhh1[64 + jcol];
    const float bxn1 = bih1[128 + jcol];
    const float bhn1 = bhh1[128 + jcol];

    float h0reg[4] = {0.f, 0.f, 0.f, 0.f};
    float h1reg[4] = {0.f, 0.f, 0.f, 0.f};
    bf16x8 h0fh[2] = {{0,0,0,0,0,0,0,0},{0,0,0,0,0,0,0,0}};  // carried h0 A-frags
    bf16x8 h0fl[2] = {{0,0,0,0,0,0,0,0},{0,0,0,0,0,0,0,0}};
    const bf16x8 zero8 = {0,0,0,0,0,0,0,0};

    // write addrs (swizzled) for this lane's 4 rows
    int widx[4];
#pragma unroll
    for (int q = 0; q < 4; ++q) widx[q] = hswz(rowgrp * 4 + q, jcol);
    // read addr base for A-frags
    int ridx[2];
#pragma unroll
    for (int kf = 0; kf < 2; ++kf)
        ridx[kf] = lrow * 64 + ((kf * 32 + rowgrp * 8) ^ ((lrow & 7) << 3));

    __syncthreads();

#pragma unroll 1
    for (int t = 0; t < T_STEPS; ++t) {
        const int buf = t & 1, nb = buf ^ 1;

        // ---- phase A: layer 0 ----
        // prefetch h1 frags (ready since last step's barrier) + x frags
        bf16x8 h1fh[2], h1fl[2];
#pragma unroll
        for (int kf = 0; kf < 2; ++kf) {
            h1fh[kf] = *(const bf16x8*)&h1s[buf][0][ridx[kf]];
            h1fl[kf] = *(const bf16x8*)&h1s[buf][1][ridx[kf]];
        }
        bf16x8 xfh = *(const bf16x8*)&xhi[t][lrow][0];
        bf16x8 xfl = *(const bf16x8*)&xlo[t][lrow][0];
        xfh = (rowgrp == 0) ? xfh : zero8;
        xfl = (rowgrp == 0) ? xfl : zero8;

        f32x4 accr = {br0, br0, br0, br0};
        f32x4 accz = {bz0, bz0, bz0, bz0};
        f32x4 accxn = {bxn0, bxn0, bxn0, bxn0};
        f32x4 acchn = {bhn0, bhn0, bhn0, bhn0};

        accr = MFMA16(xfh, wxbhi[0], accr);
        accr = MFMA16(xfl, wxbhi[0], accr);
        accr = MFMA16(xfh, wxblo[0], accr);
        accz = MFMA16(xfh, wxbhi[1], accz);
        accz = MFMA16(xfl, wxbhi[1], accz);
        accz = MFMA16(xfh, wxblo[1], accz);
        accxn = MFMA16(xfh, wxbhi[2], accxn);
        accxn = MFMA16(xfl, wxbhi[2], accxn);
        accxn = MFMA16(xfh, wxblo[2], accxn);
#pragma unroll
        for (int kf = 0; kf < 2; ++kf) {
            accr = MFMA16(h0fh[kf], w0hi[0][kf], accr);
            accr = MFMA16(h0fh[kf], w0lo[0][kf], accr);
            accr = MFMA16(h0fl[kf], w0hi[0][kf], accr);
            accz = MFMA16(h0fh[kf], w0hi[1][kf], accz);
            accz = MFMA16(h0fh[kf], w0lo[1][kf], accz);
            accz = MFMA16(h0fl[kf], w0hi[1][kf], accz);
            acchn = MFMA16(h0fh[kf], w0hi[2][kf], acchn);
            acchn = MFMA16(h0fh[kf], w0lo[2][kf], acchn);
            acchn = MFMA16(h0fl[kf], w0hi[2][kf], acchn);
        }
#pragma unroll
        for (int q = 0; q < 4; ++q) {
            float r = sigmoid_f(accr[q]);
            float z = sigmoid_f(accz[q]);
            float n = tanh_f(accxn[q] + r * acchn[q]);
            h0reg[q] = (1.0f - z) * n + z * h0reg[q];
        }
#pragma unroll
        for (int q = 0; q < 4; ++q) {
            float v = h0reg[q];
            unsigned short hb = bf16_rn(v);
            h0s[nb][0][widx[q]] = (short)hb;
            h0s[nb][1][widx[q]] = (short)bf16_rn(v - bf16f(hb));
        }
        __syncthreads();   // B1: h0[nb] visible

        // ---- phase B: layer 1 ----
#pragma unroll
        for (int kf = 0; kf < 2; ++kf) {
            h0fh[kf] = *(const bf16x8*)&h0s[nb][0][ridx[kf]];  // carried into next step
            h0fl[kf] = *(const bf16x8*)&h0s[nb][1][ridx[kf]];
        }
        f32x4 ar1 = {br1, br1, br1, br1};
        f32x4 az1 = {bz1, bz1, bz1, bz1};
        f32x4 axn1 = {bxn1, bxn1, bxn1, bxn1};
        f32x4 ahn1 = {bhn1, bhn1, bhn1, bhn1};
#pragma unroll
        for (int kf = 0; kf < 2; ++kf) {
            ar1 = MFMA16(h0fh[kf], wxhi[0][kf], ar1);
            ar1 = MFMA16(h0fh[kf], wxlo[0][kf], ar1);
            ar1 = MFMA16(h0fl[kf], wxhi[0][kf], ar1);
            ar1 = MFMA16(h1fh[kf], whhi[0][kf], ar1);
            ar1 = MFMA16(h1fh[kf], whlo[0][kf], ar1);
            ar1 = MFMA16(h1fl[kf], whhi[0][kf], ar1);

            az1 = MFMA16(h0fh[kf], wxhi[1][kf], az1);
            az1 = MFMA16(h0fh[kf], wxlo[1][kf], az1);
            az1 = MFMA16(h0fl[kf], wxhi[1][kf], az1);
            az1 = MFMA16(h1fh[kf], whhi[1][kf], az1);
            az1 = MFMA16(h1fh[kf], whlo[1][kf], az1);
            az1 = MFMA16(h1fl[kf], whhi[1][kf], az1);

            axn1 = MFMA16(h0fh[kf], wxhi[2][kf], axn1);
            axn1 = MFMA16(h0fh[kf], wxlo[2][kf], axn1);
            axn1 = MFMA16(h0fl[kf], wxhi[2][kf], axn1);

            ahn1 = MFMA16(h1fh[kf], whhi[2][kf], ahn1);
            ahn1 = MFMA16(h1fh[kf], whlo[2][kf], ahn1);
            ahn1 = MFMA16(h1fl[kf], whhi[2][kf], ahn1);
        }
#pragma unroll
        for (int q = 0; q < 4; ++q) {
            float r = sigmoid_f(ar1[q]);
            float z = sigmoid_f(az1[q]);
            float n = tanh_f(axn1[q] + r * ahn1[q]);
            h1reg[q] = (1.0f - z) * n + z * h1reg[q];
        }
#pragma unroll
        for (int q = 0; q < 4; ++q) {
            float v = h1reg[q];
            unsigned short hb = bf16_rn(v);
            h1s[nb][0][widx[q]] = (short)hb;
            h1s[nb][1][widx[q]] = (short)bf16_rn(v - bf16f(hb));
        }
        __syncthreads();   // B2: h1[nb] visible
    }

    // epilogue: final hidden + BN1 column sums
#pragma unroll
    for (int q = 0; q < 4; ++q)
        hidden[(long)(rbase + rowgrp * 4 + q) * 64 + jcol] = h1reg[q];

    float sv_ = 0.f, sq_ = 0.f;
#pragma unroll
    for (int q = 0; q < 4; ++q) { sv_ += h1reg[q]; sq_ += h1reg[q] * h1reg[q]; }
    sv_ += __shfl_xor(sv_, 16); sq_ += __shfl_xor(sq_, 16);
    sv_ += __shfl_xor(sv_, 32); sq_ += __shfl_xor(sq_, 32);
    if (rowgrp == 0) {
        atomicAdd(&colsum[jcol], sv_);
        atomicAdd(&colsumsq[jcol], sq_);
    }
}

// G = hbn^T hbn (64x64) partial-accumulated over 4 tiles of 128 rows,
// s[j] = sum_n e[n] hbn[n,j].  bn1 coefficients computed inline.
__global__ __launch_bounds__(256)
void stats_kernel(const float* __restrict__ hidden, const float* __restrict__ colsum,
                  const float* __restrict__ colsumsq, const float* __restrict__ bnw,
                  const float* __restrict__ bnb, float* __restrict__ G,
                  float* __restrict__ s)
{
    __shared__ float a1s[64], c1s[64];
    __shared__ float tile[128][65];
    __shared__ float el[128];
    const int b = blockIdx.x, tid = threadIdx.x;
    if (tid < 64) {
        float m = colsum[tid] * (1.0f / N_ROWS);
        float v = colsumsq[tid] * (1.0f / N_ROWS) - m * m;
        float a = bnw[tid] * rsqrtf(v + 1e-5f);
        a1s[tid] = a;
        c1s[tid] = bnb[tid] - m * a;
    }
    __syncthreads();

    const int j = tid & 63, kg = tid >> 6;
    float accG[16];
#pragma unroll
    for (int q = 0; q < 16; ++q) accG[q] = 0.0f;
    float accS = 0.0f;

    for (int tt = 0; tt < 4; ++tt) {
        __syncthreads();  // WAR on tile/el
        const long r0 = (long)b * 512 + tt * 128;
        for (int i = tid; i < 128 * 64; i += 256) {
            int r = i >> 6, c = i & 63;
            tile[r][c] = hidden[(r0 + r) * 64 + c] * a1s[c] + c1s[c];
        }
        __syncthreads();
        for (int r = tid; r < 128; r += 256) {
            float sum = 0.0f;
#pragma unroll 8
            for (int c = 0; c < 64; ++c) sum += tile[r][c];
            el[r] = sum * (1.0f / 64.0f);
        }
        __syncthreads();
        for (int r = 0; r < 128; ++r) {
            float hj = tile[r][j];
#pragma unroll
            for (int q = 0; q < 16; ++q) accG[q] += tile[r][kg * 16 + q] * hj;
        }
        if (tid < 64) {
            for (int r = 0; r < 128; ++r) accS += el[r] * tile[r][tid];
        }
    }
#pragma unroll
    for (int q = 0; q < 16; ++q) atomicAdd(&G[(kg * 16 + q) * 64 + j], accG[q]);
    if (tid < 64) atomicAdd(&s[tid], accS);
}

// out2[n,p] = hbn[n,:].M[:,p] - e[n]*sv[p] + fc_b[p];  M = G fc_w^T / 64
// (M, sv, bn1 coeffs, e all computed inline).  bn2 stats via atomics.
__global__ __launch_bounds__(256)
void out2_kernel(const float* __restrict__ hidden, const float* __restrict__ colsum,
                 const float* __restrict__ colsumsq, const float* __restrict__ bnw,
                 const float* __restrict__ bnb, const float* __restrict__ G,
                 const float* __restrict__ s, const float* __restrict__ fcw,
                 const float* __restrict__ fcb, float* __restrict__ out2,
                 float* __restrict__ colsum2, float* __restrict__ colsumsq2)
{
    __shared__ float a1s[64], c1s[64], svs[64];
    __shared__ float Ms[64][65];
    __shared__ float tile[128][65];
    __shared__ float el[128];
    const int b = blockIdx.x, tid = threadIdx.x;
    if (tid < 64) {
        float m = colsum[tid] * (1.0f / N_ROWS);
        float v = colsumsq[tid] * (1.0f / N_ROWS) - m * m;
        float a = bnw[tid] * rsqrtf(v + 1e-5f);
        a1s[tid] = a;
        c1s[tid] = bnb[tid] - m * a;
    }
    __syncthreads();
    // M[k][p] and sv[p]
    for (int i = tid; i < 4096; i += 256) {
        int k = i >> 6, p = i & 63;
        float acc = 0.0f;
#pragma unroll 8
        for (int jj = 0; jj < 64; ++jj) acc += G[k * 64 + jj] * fcw[p * 64 + jj];
        Ms[k][p] = acc * (1.0f / 64.0f);
    }
    if (tid < 64) {
        float acc = 0.0f;
#pragma unroll 8
        for (int jj = 0; jj < 64; ++jj) acc += s[jj] * fcw[tid * 64 + jj];
        svs[tid] = acc;
    }
    // hbn tile
    for (int i = tid; i < 128 * 64; i += 256) {
        int r = i >> 6, c = i & 63;
        tile[r][c] = hidden[(long)(b * 128 + r) * 64 + c] * a1s[c] + c1s[c];
    }
    __syncthreads();
    for (int r = tid; r < 128; r += 256) {
        float sum = 0.0f;
#pragma unroll 8
        for (int c = 0; c < 64; ++c) sum += tile[r][c];
        el[r] = sum * (1.0f / 64.0f);
    }
    __syncthreads();

    const int p = tid & 63, rq = tid >> 6;
    float sum = 0.0f, sumsq = 0.0f;
#pragma unroll 1
    for (int r = rq; r < 128; r += 4) {
        float acc = 0.0f;
#pragma unroll 8
        for (int k = 0; k < 64; ++k) acc += tile[r][k] * Ms[k][p];
        float v = acc - el[r] * svs[p] + fcb[p];
        out2[(long)(b * 128 + r) * 64 + p] = v;
        sum += v; sumsq += v * v;
    }
    atomicAdd(&colsum2[p], sum);
    atomicAdd(&colsumsq2[p], sumsq);
}

// y[n] = sum_p lrelu(bn2(out2[n,p])) * wout[p] + bout  (bn2 coeffs inline)
__global__ __launch_bounds__(256)
void final_kernel(const float* __restrict__ out2, const float* __restrict__ colsum2,
                  const float* __restrict__ colsumsq2, const float* __restrict__ bnw,
                  const float* __restrict__ bnb, const float* __restrict__ wout,
                  const float* __restrict__ bout, float* __restrict__ y)
{
    __shared__ float a2s[64], c2s[64];
    const int tid = threadIdx.x;
    if (tid < 64) {
        float m = colsum2[tid] * (1.0f / N_ROWS);
        float v = colsumsq2[tid] * (1.0f / N_ROWS) - m * m;
        float a = bnw[tid] * rsqrtf(v + 1e-5f);
        a2s[tid] = a;
        c2s[tid] = bnb[tid] - m * a;
    }
    __syncthreads();
    const int n = blockIdx.x * 256 + tid;
    float acc = bout[0];
#pragma unroll 8
    for (int p = 0; p < 64; ++p) {
        float v = out2[(long)n * 64 + p] * a2s[p] + c2s[p];
        v = (v >= 0.0f) ? v : 0.01f * v;
        acc += v * wout[p];
    }
    y[n] = acc;
}

extern "C" void kernel_launch(void* const* d_in, const int* in_sizes, int n_in,
                              void* d_out, int out_size, void* d_ws, size_t ws_size,
                              hipStream_t stream)
{
    const float* x    = (const float*)d_in[0];
    const float* Wih0 = (const float*)d_in[1];
    const float* Whh0 = (const float*)d_in[2];
    const float* bih0 = (const float*)d_in[3];
    const float* bhh0 = (const float*)d_in[4];
    const float* Wih1 = (const float*)d_in[5];
    const float* Whh1 = (const float*)d_in[6];
    const float* bih1 = (const float*)d_in[7];
    const float* bhh1 = (const float*)d_in[8];
    const float* bn1w = (const float*)d_in[9];
    const float* bn1b = (const float*)d_in[10];
    const float* fcw  = (const float*)d_in[11];
    const float* fcb  = (const float*)d_in[12];
    const float* bn2w = (const float*)d_in[13];
    const float* bn2b = (const float*)d_in[14];
    const float* fow  = (const float*)d_in[15];
    const float* fob  = (const float*)d_in[16];
    float* y = (float*)d_out;

    float* ws = (float*)d_ws;
    float* hidden = ws;                  // 8192*64
    float* out2   = ws + 524288;         // 8192*64
    float* sm     = ws + 1048576;
    float* colsum   = sm;                // 64   } zeroed
    float* colsumsq = sm + 64;           // 64   } zeroed
    float* G        = sm + 128;          // 4096 } zeroed
    float* s        = sm + 4224;         // 64   } zeroed
    float* colsum2  = sm + 4288;         // 64   } zeroed
    float* colsumsq2= sm + 4352;         // 64   } zeroed

    hipMemsetAsync(colsum, 0, 4416 * sizeof(float), stream);

    gru_fused<<<512, 256, 0, stream>>>(x, Wih0, Whh0, bih0, bhh0,
                                       Wih1, Whh1, bih1, bhh1,
                                       hidden, colsum, colsumsq);
    stats_kernel<<<16, 256, 0, stream>>>(hidden, colsum, colsumsq, bn1w, bn1b, G, s);
    out2_kernel<<<64, 256, 0, stream>>>(hidden, colsum, colsumsq, bn1w, bn1b,
                                        G, s, fcw, fcb, out2, colsum2, colsumsq2);
    final_kernel<<<32, 256, 0, stream>>>(out2, colsum2, colsumsq2, bn2w, bn2b,
                                         fow, fob, y);
}

// Round 4
// 303.669 us; speedup vs baseline: 25.1413x; 1.5228x over previous
//
#include <hip/hip_runtime.h>
#include <hip/hip_bf16.h>

#define N_ROWS 8192
#define T_STEPS 60
#define HDIM 64
#define DFEAT 6

typedef _Float16 f16x8 __attribute__((ext_vector_type(8)));
typedef float f32x4 __attribute__((ext_vector_type(4)));
typedef float fvec4 __attribute__((ext_vector_type(4)));

__device__ __forceinline__ float sigmoid_f(float x) {
    return 1.0f / (1.0f + __expf(-x));
}
__device__ __forceinline__ float tanh_f(float x) {
    float ax = fabsf(x);
    float t = __expf(-2.0f * ax);
    float r = (1.0f - t) / (1.0f + t);
    return copysignf(r, x);
}

#define MFMA16(a, b, c) __builtin_amdgcn_mfma_f32_16x16x32_f16(a, b, c, 0, 0, 0)

// Load 8 consecutive fp32 weights W[(g*64+jcol)][kf*32+rowgrp*8 .. +8) as an
// fp16 B-fragment (col=lane&15, k=(lane>>4)*8+e).  |W|<=1/8 -> fp16 safe.
#define LOAD_W(W, g, kf, DST) do {                                            \
    const float* _p = (W) + ((g)*64 + jcol)*64 + (kf)*32 + rowgrp*8;          \
    fvec4 _v0 = *(const fvec4*)_p;                                            \
    fvec4 _v1 = *(const fvec4*)(_p + 4);                                      \
    f16x8 _f;                                                                 \
    _Pragma("unroll")                                                         \
    for (int _e = 0; _e < 4; ++_e) {                                          \
        _f[_e]     = (_Float16)_v0[_e];                                       \
        _f[4 + _e] = (_Float16)_v1[_e];                                       \
    }                                                                         \
    DST = _f;                                                                 \
} while (0)

// swizzled LDS index for h planes: (row, col) -> row*64 + (col ^ ((row&7)<<3))
__device__ __forceinline__ int hswz(int row, int col) {
    return row * 64 + (col ^ ((row & 7) << 3));
}

// Persistent MFMA GRU. 512 blocks x 256 threads (4 waves).
// Block owns 16 rows; wave wv owns output columns [16*wv, 16*wv+16).
// fp16 single-plane state + weights (|h|<=1, |W|<=1/8 -> fp16-safe; 2^-11 rel).
// 21 MFMA/step.  h planes double-buffered, XOR-swizzled.  2 barriers/step.
__global__ __launch_bounds__(256, 2)
void gru_fused(const float* __restrict__ x,
               const float* __restrict__ Wih0, const float* __restrict__ Whh0,
               const float* __restrict__ bih0, const float* __restrict__ bhh0,
               const float* __restrict__ Wih1, const float* __restrict__ Whh1,
               const float* __restrict__ bih1, const float* __restrict__ bhh1,
               float* __restrict__ hidden, float* __restrict__ colsum,
               float* __restrict__ colsumsq)
{
    __shared__ __align__(16) _Float16 h0s[2][1024];   // [buf][swizzled 16x64]
    __shared__ __align__(16) _Float16 h1s[2][1024];
    __shared__ __align__(16) _Float16 xs[T_STEPS][16][8];  // per-step x A-frags

    const int tid = threadIdx.x;
    const int lane = tid & 63;
    const int wv = tid >> 6;          // 0..3
    const int lrow = lane & 15;       // A row / C col-within-tile
    const int rowgrp = lane >> 4;     // 0..3
    const int jcol = wv * 16 + lrow;  // this lane's output column (0..63)
    const int rbase = blockIdx.x * 16;

    // zero h planes
    for (int i = tid; i < 2 * 1024; i += 256) {
        h0s[0][i & 1023] = (_Float16)0.f;  // i<1024 -> buf0, else buf1
        h0s[1][i & 1023] = (_Float16)0.f;
        h1s[0][i & 1023] = (_Float16)0.f;
        h1s[1][i & 1023] = (_Float16)0.f;
    }
    // stage x -> per-step A-fragments
    for (int idx = tid; idx < 16 * T_STEPS; idx += 256) {
        int t = idx >> 4, r = idx & 15;
        const float* xp = x + (long)(rbase + r) * (DFEAT * T_STEPS) + t;
        f16x8 f;
#pragma unroll
        for (int d = 0; d < DFEAT; ++d) f[d] = (_Float16)xp[d * T_STEPS];
        f[6] = (_Float16)0.f; f[7] = (_Float16)0.f;
        *(f16x8*)&xs[t][r][0] = f;
    }

    // ---- weight fragments in registers (once) ----
    f16x8 w0[3][2];   // Whh0
    f16x8 wx[3][2];   // Wih1
    f16x8 wh[3][2];   // Whh1
#pragma unroll
    for (int g = 0; g < 3; ++g) {
#pragma unroll
        for (int kf = 0; kf < 2; ++kf) {
            LOAD_W(Whh0, g, kf, w0[g][kf]);
            LOAD_W(Wih1, g, kf, wx[g][kf]);
            LOAD_W(Whh1, g, kf, wh[g][kf]);
        }
    }
    // x-part B-fragments (K=6 zero-padded; only rowgrp 0 lanes carry data)
    f16x8 wxb[3];
#pragma unroll
    for (int g = 0; g < 3; ++g) {
        f16x8 f;
#pragma unroll
        for (int e = 0; e < 8; ++e) f[e] = (_Float16)0.f;
        if (rowgrp == 0) {
#pragma unroll
            for (int e = 0; e < DFEAT; ++e)
                f[e] = (_Float16)Wih0[(g * 64 + jcol) * DFEAT + e];
        }
        wxb[g] = f;
    }

    const float br0  = bih0[jcol] + bhh0[jcol];
    const float bz0  = bih0[64 + jcol] + bhh0[64 + jcol];
    const float bxn0 = bih0[128 + jcol];
    const float bhn0 = bhh0[128 + jcol];
    const float br1  = bih1[jcol] + bhh1[jcol];
    const float bz1  = bih1[64 + jcol] + bhh1[64 + jcol];
    const float bxn1 = bih1[128 + jcol];
    const float bhn1 = bhh1[128 + jcol];

    float h0reg[4] = {0.f, 0.f, 0.f, 0.f};
    float h1reg[4] = {0.f, 0.f, 0.f, 0.f};
    f16x8 h0f[2];
    f16x8 zerof;
#pragma unroll
    for (int e = 0; e < 8; ++e) zerof[e] = (_Float16)0.f;
    h0f[0] = zerof; h0f[1] = zerof;

    // write addrs (swizzled) for this lane's 4 rows
    int widx[4];
#pragma unroll
    for (int q = 0; q < 4; ++q) widx[q] = hswz(rowgrp * 4 + q, jcol);
    // read addr base for A-frags
    int ridx[2];
#pragma unroll
    for (int kf = 0; kf < 2; ++kf)
        ridx[kf] = lrow * 64 + ((kf * 32 + rowgrp * 8) ^ ((lrow & 7) << 3));

    __syncthreads();

#pragma unroll 1
    for (int t = 0; t < T_STEPS; ++t) {
        const int buf = t & 1, nb = buf ^ 1;

        // ---- phase A: layer 0 ----
        f16x8 h1f[2];
#pragma unroll
        for (int kf = 0; kf < 2; ++kf)
            h1f[kf] = *(const f16x8*)&h1s[buf][ridx[kf]];
        f16x8 xf = *(const f16x8*)&xs[t][lrow][0];
        xf = (rowgrp == 0) ? xf : zerof;

        f32x4 accr  = {br0, br0, br0, br0};
        f32x4 accz  = {bz0, bz0, bz0, bz0};
        f32x4 accxn = {bxn0, bxn0, bxn0, bxn0};
        f32x4 acchn = {bhn0, bhn0, bhn0, bhn0};

        accr  = MFMA16(xf, wxb[0], accr);
        accz  = MFMA16(xf, wxb[1], accz);
        accxn = MFMA16(xf, wxb[2], accxn);
#pragma unroll
        for (int kf = 0; kf < 2; ++kf) {
            accr  = MFMA16(h0f[kf], w0[0][kf], accr);
            accz  = MFMA16(h0f[kf], w0[1][kf], accz);
            acchn = MFMA16(h0f[kf], w0[2][kf], acchn);
        }
#pragma unroll
        for (int q = 0; q < 4; ++q) {
            float r = sigmoid_f(accr[q]);
            float z = sigmoid_f(accz[q]);
            float n = tanh_f(accxn[q] + r * acchn[q]);
            h0reg[q] = (1.0f - z) * n + z * h0reg[q];
        }
#pragma unroll
        for (int q = 0; q < 4; ++q)
            h0s[nb][widx[q]] = (_Float16)h0reg[q];
        __syncthreads();   // B1: h0[nb] visible

        // ---- phase B: layer 1 ----
#pragma unroll
        for (int kf = 0; kf < 2; ++kf)
            h0f[kf] = *(const f16x8*)&h0s[nb][ridx[kf]];  // carried to next step

        f32x4 ar1  = {br1, br1, br1, br1};
        f32x4 az1  = {bz1, bz1, bz1, bz1};
        f32x4 axn1 = {bxn1, bxn1, bxn1, bxn1};
        f32x4 ahn1 = {bhn1, bhn1, bhn1, bhn1};
#pragma unroll
        for (int kf = 0; kf < 2; ++kf) {
            ar1  = MFMA16(h0f[kf], wx[0][kf], ar1);
            ar1  = MFMA16(h1f[kf], wh[0][kf], ar1);
            az1  = MFMA16(h0f[kf], wx[1][kf], az1);
            az1  = MFMA16(h1f[kf], wh[1][kf], az1);
            axn1 = MFMA16(h0f[kf], wx[2][kf], axn1);
            ahn1 = MFMA16(h1f[kf], wh[2][kf], ahn1);
        }
#pragma unroll
        for (int q = 0; q < 4; ++q) {
            float r = sigmoid_f(ar1[q]);
            float z = sigmoid_f(az1[q]);
            float n = tanh_f(axn1[q] + r * ahn1[q]);
            h1reg[q] = (1.0f - z) * n + z * h1reg[q];
        }
#pragma unroll
        for (int q = 0; q < 4; ++q)
            h1s[nb][widx[q]] = (_Float16)h1reg[q];
        __syncthreads();   // B2: h1[nb] visible
    }

    // epilogue: final hidden + BN1 column sums
#pragma unroll
    for (int q = 0; q < 4; ++q)
        hidden[(long)(rbase + rowgrp * 4 + q) * 64 + jcol] = h1reg[q];

    float sv_ = 0.f, sq_ = 0.f;
#pragma unroll
    for (int q = 0; q < 4; ++q) { sv_ += h1reg[q]; sq_ += h1reg[q] * h1reg[q]; }
    sv_ += __shfl_xor(sv_, 16); sq_ += __shfl_xor(sq_, 16);
    sv_ += __shfl_xor(sv_, 32); sq_ += __shfl_xor(sq_, 32);
    if (rowgrp == 0) {
        atomicAdd(&colsum[jcol], sv_);
        atomicAdd(&colsumsq[jcol], sq_);
    }
}

// G = hbn^T hbn (64x64), s[j] = sum_n e[n] hbn[n,j].  64 blocks x 128 rows.
// bn1 coefficients computed inline.
__global__ __launch_bounds__(256)
void stats_kernel(const float* __restrict__ hidden, const float* __restrict__ colsum,
                  const float* __restrict__ colsumsq, const float* __restrict__ bnw,
                  const float* __restrict__ bnb, float* __restrict__ G,
                  float* __restrict__ s)
{
    __shared__ float a1s[64], c1s[64];
    __shared__ float tile[128][65];
    __shared__ float el[128];
    const int b = blockIdx.x, tid = threadIdx.x;
    if (tid < 64) {
        float m = colsum[tid] * (1.0f / N_ROWS);
        float v = colsumsq[tid] * (1.0f / N_ROWS) - m * m;
        float a = bnw[tid] * rsqrtf(v + 1e-5f);
        a1s[tid] = a;
        c1s[tid] = bnb[tid] - m * a;
    }
    __syncthreads();

    const long r0 = (long)b * 128;
    for (int i = tid; i < 128 * 64; i += 256) {
        int r = i >> 6, c = i & 63;
        tile[r][c] = hidden[(r0 + r) * 64 + c] * a1s[c] + c1s[c];
    }
    __syncthreads();
    for (int r = tid; r < 128; r += 256) {
        float sum = 0.0f;
#pragma unroll 8
        for (int c = 0; c < 64; ++c) sum += tile[r][c];
        el[r] = sum * (1.0f / 64.0f);
    }
    __syncthreads();

    const int j = tid & 63, kg = tid >> 6;
    float accG[16];
#pragma unroll
    for (int q = 0; q < 16; ++q) accG[q] = 0.0f;
    for (int r = 0; r < 128; ++r) {
        float hj = tile[r][j];
#pragma unroll
        for (int q = 0; q < 16; ++q) accG[q] += tile[r][kg * 16 + q] * hj;
    }
#pragma unroll
    for (int q = 0; q < 16; ++q) atomicAdd(&G[(kg * 16 + q) * 64 + j], accG[q]);
    if (tid < 64) {
        float accS = 0.0f;
        for (int r = 0; r < 128; ++r) accS += el[r] * tile[r][tid];
        atomicAdd(&s[tid], accS);
    }
}

// out2[n,p] = hbn[n,:].M[:,p] - e[n]*sv[p] + fc_b[p];  M = G fc_w^T / 64
// (M, sv, bn1 coeffs, e all computed inline).  bn2 stats via atomics.
__global__ __launch_bounds__(256)
void out2_kernel(const float* __restrict__ hidden, const float* __restrict__ colsum,
                 const float* __restrict__ colsumsq, const float* __restrict__ bnw,
                 const float* __restrict__ bnb, const float* __restrict__ G,
                 const float* __restrict__ s, const float* __restrict__ fcw,
                 const float* __restrict__ fcb, float* __restrict__ out2,
                 float* __restrict__ colsum2, float* __restrict__ colsumsq2)
{
    __shared__ float a1s[64], c1s[64], svs[64];
    __shared__ float Ms[64][65];
    __shared__ float tile[128][65];
    __shared__ float el[128];
    const int b = blockIdx.x, tid = threadIdx.x;
    if (tid < 64) {
        float m = colsum[tid] * (1.0f / N_ROWS);
        float v = colsumsq[tid] * (1.0f / N_ROWS) - m * m;
        float a = bnw[tid] * rsqrtf(v + 1e-5f);
        a1s[tid] = a;
        c1s[tid] = bnb[tid] - m * a;
    }
    __syncthreads();
    // M[k][p] and sv[p]
    for (int i = tid; i < 4096; i += 256) {
        int k = i >> 6, p = i & 63;
        float acc = 0.0f;
#pragma unroll 8
        for (int jj = 0; jj < 64; ++jj) acc += G[k * 64 + jj] * fcw[p * 64 + jj];
        Ms[k][p] = acc * (1.0f / 64.0f);
    }
    if (tid < 64) {
        float acc = 0.0f;
#pragma unroll 8
        for (int jj = 0; jj < 64; ++jj) acc += s[jj] * fcw[tid * 64 + jj];
        svs[tid] = acc;
    }
    // hbn tile
    for (int i = tid; i < 128 * 64; i += 256) {
        int r = i >> 6, c = i & 63;
        tile[r][c] = hidden[(long)(b * 128 + r) * 64 + c] * a1s[c] + c1s[c];
    }
    __syncthreads();
    for (int r = tid; r < 128; r += 256) {
        float sum = 0.0f;
#pragma unroll 8
        for (int c = 0; c < 64; ++c) sum += tile[r][c];
        el[r] = sum * (1.0f / 64.0f);
    }
    __syncthreads();

    const int p = tid & 63, rq = tid >> 6;
    float sum = 0.0f, sumsq = 0.0f;
#pragma unroll 1
    for (int r = rq; r < 128; r += 4) {
        float acc = 0.0f;
#pragma unroll 8
        for (int k = 0; k < 64; ++k) acc += tile[r][k] * Ms[k][p];
        float v = acc - el[r] * svs[p] + fcb[p];
        out2[(long)(b * 128 + r) * 64 + p] = v;
        sum += v; sumsq += v * v;
    }
    atomicAdd(&colsum2[p], sum);
    atomicAdd(&colsumsq2[p], sumsq);
}

// y[n] = sum_p lrelu(bn2(out2[n,p])) * wout[p] + bout  (bn2 coeffs inline)
__global__ __launch_bounds__(256)
void final_kernel(const float* __restrict__ out2, const float* __restrict__ colsum2,
                  const float* __restrict__ colsumsq2, const float* __restrict__ bnw,
                  const float* __restrict__ bnb, const float* __restrict__ wout,
                  const float* __restrict__ bout, float* __restrict__ y)
{
    __shared__ float a2s[64], c2s[64];
    const int tid = threadIdx.x;
    if (tid < 64) {
        float m = colsum2[tid] * (1.0f / N_ROWS);
        float v = colsumsq2[tid] * (1.0f / N_ROWS) - m * m;
        float a = bnw[tid] * rsqrtf(v + 1e-5f);
        a2s[tid] = a;
        c2s[tid] = bnb[tid] - m * a;
    }
    __syncthreads();
    const int n = blockIdx.x * 256 + tid;
    float acc = bout[0];
#pragma unroll 8
    for (int p = 0; p < 64; ++p) {
        float v = out2[(long)n * 64 + p] * a2s[p] + c2s[p];
        v = (v >= 0.0f) ? v : 0.01f * v;
        acc += v * wout[p];
    }
    y[n] = acc;
}

extern "C" void kernel_launch(void* const* d_in, const int* in_sizes, int n_in,
                              void* d_out, int out_size, void* d_ws, size_t ws_size,
                              hipStream_t stream)
{
    const float* x    = (const float*)d_in[0];
    const float* Wih0 = (const float*)d_in[1];
    const float* Whh0 = (const float*)d_in[2];
    const float* bih0 = (const float*)d_in[3];
    const float* bhh0 = (const float*)d_in[4];
    const float* Wih1 = (const float*)d_in[5];
    const float* Whh1 = (const float*)d_in[6];
    const float* bih1 = (const float*)d_in[7];
    const float* bhh1 = (const float*)d_in[8];
    const float* bn1w = (const float*)d_in[9];
    const float* bn1b = (const float*)d_in[10];
    const float* fcw  = (const float*)d_in[11];
    const float* fcb  = (const float*)d_in[12];
    const float* bn2w = (const float*)d_in[13];
    const float* bn2b = (const float*)d_in[14];
    const float* fow  = (const float*)d_in[15];
    const float* fob  = (const float*)d_in[16];
    float* y = (float*)d_out;

    float* ws = (float*)d_ws;
    float* hidden = ws;                  // 8192*64
    float* out2   = ws + 524288;         // 8192*64
    float* sm     = ws + 1048576;
    float* colsum   = sm;                // 64   } zeroed
    float* colsumsq = sm + 64;           // 64   } zeroed
    float* G        = sm + 128;          // 4096 } zeroed
    float* s        = sm + 4224;         // 64   } zeroed
    float* colsum2  = sm + 4288;         // 64   } zeroed
    float* colsumsq2= sm + 4352;         // 64   } zeroed

    hipMemsetAsync(colsum, 0, 4416 * sizeof(float), stream);

    gru_fused<<<512, 256, 0, stream>>>(x, Wih0, Whh0, bih0, bhh0,
                                       Wih1, Whh1, bih1, bhh1,
                                       hidden, colsum, colsumsq);
    stats_kernel<<<64, 256, 0, stream>>>(hidden, colsum, colsumsq, bn1w, bn1b, G, s);
    out2_kernel<<<64, 256, 0, stream>>>(hidden, colsum, colsumsq, bn1w, bn1b,
                                        G, s, fcw, fcb, out2, colsum2, colsumsq2);
    final_kernel<<<32, 256, 0, stream>>>(out2, colsum2, colsumsq2, bn2w, bn2b,
                                         fow, fob, y);
}

// Round 5
// 235.560 us; speedup vs baseline: 32.4105x; 1.2891x over previous
//
#include <hip/hip_runtime.h>
#include <hip/hip_bf16.h>

#define N_ROWS 8192
#define T_STEPS 60
#define HDIM 64
#define DFEAT 6

typedef _Float16 f16x8 __attribute__((ext_vector_type(8)));
typedef float f32x4 __attribute__((ext_vector_type(4)));
typedef float fvec4 __attribute__((ext_vector_type(4)));

__device__ __forceinline__ float fast_rcp(float x) {
    return __builtin_amdgcn_rcpf(x);
}
__device__ __forceinline__ float sigmoid_f(float x) {
    return fast_rcp(1.0f + __expf(-x));
}
__device__ __forceinline__ float tanh_f(float x) {
    // 2/(1+e^-2x) - 1 ; saturates correctly at +-1, no div/abs/copysign
    float t = __expf(-2.0f * x);
    return 2.0f * fast_rcp(1.0f + t) - 1.0f;
}

#define MFMA16(a, b, c) __builtin_amdgcn_mfma_f32_16x16x32_f16(a, b, c, 0, 0, 0)

// Load 8 consecutive fp32 weights W[(g*64+jcol)][kf*32+rowgrp*8 .. +8) as an
// fp16 B-fragment (col=lane&15, k=(lane>>4)*8+e).  |W|<=1/8 -> fp16 safe.
#define LOAD_W(W, g, kf, DST) do {                                            \
    const float* _p = (W) + ((g)*64 + jcol)*64 + (kf)*32 + rowgrp*8;          \
    fvec4 _v0 = *(const fvec4*)_p;                                            \
    fvec4 _v1 = *(const fvec4*)(_p + 4);                                      \
    f16x8 _f;                                                                 \
    _Pragma("unroll")                                                         \
    for (int _e = 0; _e < 4; ++_e) {                                          \
        _f[_e]     = (_Float16)_v0[_e];                                       \
        _f[4 + _e] = (_Float16)_v1[_e];                                       \
    }                                                                         \
    DST = _f;                                                                 \
} while (0)

// swizzled LDS index for h planes: (row, col) -> row*64 + (col ^ ((row&7)<<3))
__device__ __forceinline__ int hswz(int row, int col) {
    return row * 64 + (col ^ ((row & 7) << 3));
}

// One GRU timestep (both layers).  BUF/NB are compile-time 0/1 after unroll.
#define GRU_STEP(tt, BUF, NB) do {                                            \
    /* phase A: layer 0 */                                                    \
    f16x8 h1f0 = *(const f16x8*)&h1s[BUF][ridx0];                             \
    f16x8 h1f1 = *(const f16x8*)&h1s[BUF][ridx1];                             \
    f16x8 xf = *(const f16x8*)(xbase_l + (tt) * xinc);                        \
    f32x4 accr  = {br0, br0, br0, br0};                                       \
    f32x4 accz  = {bz0, bz0, bz0, bz0};                                       \
    f32x4 accxn = {bxn0, bxn0, bxn0, bxn0};                                   \
    f32x4 acchn = {bhn0, bhn0, bhn0, bhn0};                                   \
    accr  = MFMA16(xf, wxb[0], accr);                                         \
    accz  = MFMA16(xf, wxb[1], accz);                                         \
    accxn = MFMA16(xf, wxb[2], accxn);                                        \
    accr  = MFMA16(h0f[0], w0[0][0], accr);                                   \
    accr  = MFMA16(h0f[1], w0[0][1], accr);                                   \
    accz  = MFMA16(h0f[0], w0[1][0], accz);                                   \
    accz  = MFMA16(h0f[1], w0[1][1], accz);                                   \
    acchn = MFMA16(h0f[0], w0[2][0], acchn);                                  \
    acchn = MFMA16(h0f[1], w0[2][1], acchn);                                  \
    _Pragma("unroll")                                                         \
    for (int q = 0; q < 4; ++q) {                                             \
        float r = sigmoid_f(accr[q]);                                         \
        float z = sigmoid_f(accz[q]);                                         \
        float n = tanh_f(accxn[q] + r * acchn[q]);                            \
        h0reg[q] = n + z * (h0reg[q] - n);                                    \
    }                                                                         \
    _Pragma("unroll")                                                         \
    for (int q = 0; q < 4; ++q)                                               \
        h0s[NB][widx[q]] = (_Float16)h0reg[q];                                \
    __syncthreads();   /* B1: h0[NB] visible */                               \
    /* phase B: layer 1 */                                                    \
    h0f[0] = *(const f16x8*)&h0s[NB][ridx0];                                  \
    h0f[1] = *(const f16x8*)&h0s[NB][ridx1];                                  \
    f32x4 ar1  = {br1, br1, br1, br1};                                        \
    f32x4 az1  = {bz1, bz1, bz1, bz1};                                        \
    f32x4 axn1 = {bxn1, bxn1, bxn1, bxn1};                                    \
    f32x4 ahn1 = {bhn1, bhn1, bhn1, bhn1};                                    \
    ar1  = MFMA16(h0f[0], wx[0][0], ar1);                                     \
    ar1  = MFMA16(h0f[1], wx[0][1], ar1);                                     \
    ar1  = MFMA16(h1f0, wh[0][0], ar1);                                       \
    ar1  = MFMA16(h1f1, wh[0][1], ar1);                                       \
    az1  = MFMA16(h0f[0], wx[1][0], az1);                                     \
    az1  = MFMA16(h0f[1], wx[1][1], az1);                                     \
    az1  = MFMA16(h1f0, wh[1][0], az1);                                       \
    az1  = MFMA16(h1f1, wh[1][1], az1);                                       \
    axn1 = MFMA16(h0f[0], wx[2][0], axn1);                                    \
    axn1 = MFMA16(h0f[1], wx[2][1], axn1);                                    \
    ahn1 = MFMA16(h1f0, wh[2][0], ahn1);                                      \
    ahn1 = MFMA16(h1f1, wh[2][1], ahn1);                                      \
    _Pragma("unroll")                                                         \
    for (int q = 0; q < 4; ++q) {                                             \
        float r = sigmoid_f(ar1[q]);                                          \
        float z = sigmoid_f(az1[q]);                                          \
        float n = tanh_f(axn1[q] + r * ahn1[q]);                              \
        h1reg[q] = n + z * (h1reg[q] - n);                                    \
    }                                                                         \
    _Pragma("unroll")                                                         \
    for (int q = 0; q < 4; ++q)                                               \
        h1s[NB][widx[q]] = (_Float16)h1reg[q];                                \
    __syncthreads();   /* B2: h1[NB] visible */                               \
} while (0)

// Persistent MFMA GRU. 512 blocks x 256 threads (4 waves).
// Block owns 16 rows; wave wv owns output columns [16*wv, 16*wv+16).
// fp16 single-plane state + weights.  21 MFMA/step.  2 barriers/step.
__global__ __launch_bounds__(256, 2)
void gru_fused(const float* __restrict__ x,
               const float* __restrict__ Wih0, const float* __restrict__ Whh0,
               const float* __restrict__ bih0, const float* __restrict__ bhh0,
               const float* __restrict__ Wih1, const float* __restrict__ Whh1,
               const float* __restrict__ bih1, const float* __restrict__ bhh1,
               float* __restrict__ hidden, float* __restrict__ colsum,
               float* __restrict__ colsumsq)
{
    __shared__ __align__(16) _Float16 h0s[2][1024];   // [buf][swizzled 16x64]
    __shared__ __align__(16) _Float16 h1s[2][1024];
    __shared__ __align__(16) _Float16 xs[T_STEPS][16][8];  // per-step x A-frags
    __shared__ __align__(16) _Float16 zx[8];               // zero frag

    const int tid = threadIdx.x;
    const int lane = tid & 63;
    const int wv = tid >> 6;          // 0..3
    const int lrow = lane & 15;       // A row / C col-within-tile
    const int rowgrp = lane >> 4;     // 0..3
    const int jcol = wv * 16 + lrow;  // this lane's output column (0..63)
    const int rbase = blockIdx.x * 16;

    for (int i = tid; i < 1024; i += 256) {
        h0s[0][i] = (_Float16)0.f;
        h0s[1][i] = (_Float16)0.f;
        h1s[0][i] = (_Float16)0.f;
        h1s[1][i] = (_Float16)0.f;
    }
    if (tid < 8) zx[tid] = (_Float16)0.f;
    // stage x -> per-step A-fragments
    for (int idx = tid; idx < 16 * T_STEPS; idx += 256) {
        int t = idx >> 4, r = idx & 15;
        const float* xp = x + (long)(rbase + r) * (DFEAT * T_STEPS) + t;
        f16x8 f;
#pragma unroll
        for (int d = 0; d < DFEAT; ++d) f[d] = (_Float16)xp[d * T_STEPS];
        f[6] = (_Float16)0.f; f[7] = (_Float16)0.f;
        *(f16x8*)&xs[t][r][0] = f;
    }

    // ---- weight fragments in registers (once) ----
    f16x8 w0[3][2];   // Whh0
    f16x8 wx[3][2];   // Wih1
    f16x8 wh[3][2];   // Whh1
#pragma unroll
    for (int g = 0; g < 3; ++g) {
#pragma unroll
        for (int kf = 0; kf < 2; ++kf) {
            LOAD_W(Whh0, g, kf, w0[g][kf]);
            LOAD_W(Wih1, g, kf, wx[g][kf]);
            LOAD_W(Whh1, g, kf, wh[g][kf]);
        }
    }
    // x-part B-fragments (K=6 zero-padded; only rowgrp 0 lanes carry data)
    f16x8 wxb[3];
#pragma unroll
    for (int g = 0; g < 3; ++g) {
        f16x8 f;
#pragma unroll
        for (int e = 0; e < 8; ++e) f[e] = (_Float16)0.f;
        if (rowgrp == 0) {
#pragma unroll
            for (int e = 0; e < DFEAT; ++e)
                f[e] = (_Float16)Wih0[(g * 64 + jcol) * DFEAT + e];
        }
        wxb[g] = f;
    }

    const float br0  = bih0[jcol] + bhh0[jcol];
    const float bz0  = bih0[64 + jcol] + bhh0[64 + jcol];
    const float bxn0 = bih0[128 + jcol];
    const float bhn0 = bhh0[128 + jcol];
    const float br1  = bih1[jcol] + bhh1[jcol];
    const float bz1  = bih1[64 + jcol] + bhh1[64 + jcol];
    const float bxn1 = bih1[128 + jcol];
    const float bhn1 = bhh1[128 + jcol];

    float h0reg[4] = {0.f, 0.f, 0.f, 0.f};
    float h1reg[4] = {0.f, 0.f, 0.f, 0.f};
    f16x8 h0f[2];
#pragma unroll
    for (int e = 0; e < 8; ++e) { h0f[0][e] = (_Float16)0.f; h0f[1][e] = (_Float16)0.f; }

    // x fragment address select (loop-invariant per lane)
    const _Float16* xbase_l = (rowgrp == 0) ? &xs[0][lrow][0] : &zx[0];
    const long xinc = (rowgrp == 0) ? 128 : 0;   // halfs per t

    // write addrs (swizzled) for this lane's 4 rows
    int widx[4];
#pragma unroll
    for (int q = 0; q < 4; ++q) widx[q] = hswz(rowgrp * 4 + q, jcol);
    // read addr base for A-frags
    const int ridx0 = lrow * 64 + ((rowgrp * 8) ^ ((lrow & 7) << 3));
    const int ridx1 = lrow * 64 + ((32 + rowgrp * 8) ^ ((lrow & 7) << 3));

    __syncthreads();

#pragma unroll 1
    for (int t2 = 0; t2 < T_STEPS / 2; ++t2) {
        const int t = t2 * 2;
        GRU_STEP(t, 0, 1);
        GRU_STEP(t + 1, 1, 0);
    }

    // epilogue: final hidden + BN1 column sums
#pragma unroll
    for (int q = 0; q < 4; ++q)
        hidden[(long)(rbase + rowgrp * 4 + q) * 64 + jcol] = h1reg[q];

    float sv_ = 0.f, sq_ = 0.f;
#pragma unroll
    for (int q = 0; q < 4; ++q) { sv_ += h1reg[q]; sq_ += h1reg[q] * h1reg[q]; }
    sv_ += __shfl_xor(sv_, 16); sq_ += __shfl_xor(sq_, 16);
    sv_ += __shfl_xor(sv_, 32); sq_ += __shfl_xor(sq_, 32);
    if (rowgrp == 0) {
        atomicAdd(&colsum[jcol], sv_);
        atomicAdd(&colsumsq[jcol], sq_);
    }
}

// G = hbn^T hbn (64x64), s[j] = sum_n e[n] hbn[n,j], E2 = sum_n e[n]^2.
// 64 blocks x 128 rows.  bn1 coefficients computed inline.
__global__ __launch_bounds__(256)
void stats_kernel(const float* __restrict__ hidden, const float* __restrict__ colsum,
                  const float* __restrict__ colsumsq, const float* __restrict__ bnw,
                  const float* __restrict__ bnb, float* __restrict__ G,
                  float* __restrict__ s, float* __restrict__ E2)
{
    __shared__ float a1s[64], c1s[64];
    __shared__ float tile[128][65];
    __shared__ float el[128];
    const int b = blockIdx.x, tid = threadIdx.x;
    if (tid < 64) {
        float m = colsum[tid] * (1.0f / N_ROWS);
        float v = colsumsq[tid] * (1.0f / N_ROWS) - m * m;
        float a = bnw[tid] * rsqrtf(v + 1e-5f);
        a1s[tid] = a;
        c1s[tid] = bnb[tid] - m * a;
    }
    __syncthreads();

    const long r0 = (long)b * 128;
    for (int i = tid; i < 128 * 64; i += 256) {
        int r = i >> 6, c = i & 63;
        tile[r][c] = hidden[(r0 + r) * 64 + c] * a1s[c] + c1s[c];
    }
    __syncthreads();
    for (int r = tid; r < 128; r += 256) {
        float sum = 0.0f;
#pragma unroll 8
        for (int c = 0; c < 64; ++c) sum += tile[r][c];
        el[r] = sum * (1.0f / 64.0f);
    }
    __syncthreads();

    const int j = tid & 63, kg = tid >> 6;
    float accG[16];
#pragma unroll
    for (int q = 0; q < 16; ++q) accG[q] = 0.0f;
    for (int r = 0; r < 128; ++r) {
        float hj = tile[r][j];
#pragma unroll
        for (int q = 0; q < 16; ++q) accG[q] += tile[r][kg * 16 + q] * hj;
    }
#pragma unroll
    for (int q = 0; q < 16; ++q) atomicAdd(&G[(kg * 16 + q) * 64 + j], accG[q]);
    if (tid < 64) {
        float accS = 0.0f;
        for (int r = 0; r < 128; ++r) accS += el[r] * tile[r][tid];
        atomicAdd(&s[tid], accS);
    }
    // E2 partial: wave 0 reduces el^2
    if (tid < 64) {
        float p = el[tid] * el[tid] + el[tid + 64] * el[tid + 64];
#pragma unroll
        for (int o = 32; o > 0; o >>= 1) p += __shfl_down(p, o);
        if (tid == 0) atomicAdd(E2, p);
    }
}

// Analytic prep: M = G fcw^T/64, sv, and BN2 coefficients WITHOUT touching out2.
// Uses  sum_n hbn[n,j] = N*b1[j]  (exact BN identity):
//   Su[p]    = N*(b1^T M)[p] - (N*mean(b1))*sv[p]
//   sum u^2  = (M^T G M)[p,p] - 2 sv[p] (s^T M)[p] + E2 sv[p]^2
//   out2 = u + fcb  ->  colsum2, colsumsq2 -> a2, c2
__global__ __launch_bounds__(256)
void prep_kernel(const float* __restrict__ G, const float* __restrict__ s,
                 const float* __restrict__ E2, const float* __restrict__ fcw,
                 const float* __restrict__ fcb, const float* __restrict__ b1,
                 const float* __restrict__ bn2w, const float* __restrict__ bn2b,
                 float* __restrict__ M, float* __restrict__ sv,
                 float* __restrict__ a2, float* __restrict__ c2)
{
    __shared__ float Gs[64][65];
    __shared__ float Fs[64][64];
    __shared__ float Ms[64][65];
    __shared__ float GMs[64][65];
    const int tid = threadIdx.x;

    for (int i = tid; i < 4096; i += 256) {
        Gs[i >> 6][i & 63] = G[i];
        Fs[i >> 6][i & 63] = fcw[i];
    }
    __syncthreads();
    // M[k][p] = (1/64) sum_j G[k][j] fcw[p][j]
    for (int i = tid; i < 4096; i += 256) {
        int k = i >> 6, p = i & 63;
        float acc = 0.0f;
#pragma unroll 8
        for (int j = 0; j < 64; ++j) acc += Gs[k][j] * Fs[p][j];
        float m = acc * (1.0f / 64.0f);
        Ms[k][p] = m;
        M[i] = m;
    }
    __syncthreads();
    // GM[k][p] = sum_k' G[k][k'] M[k'][p]
    for (int i = tid; i < 4096; i += 256) {
        int k = i >> 6, p = i & 63;
        float acc = 0.0f;
#pragma unroll 8
        for (int kk = 0; kk < 64; ++kk) acc += Gs[k][kk] * Ms[kk][p];
        GMs[k][p] = acc;
    }
    __syncthreads();
    if (tid < 64) {
        const int p = tid;
        float svp = 0.0f, A = 0.0f, B = 0.0f, bM = 0.0f, bsum = 0.0f;
#pragma unroll 8
        for (int j = 0; j < 64; ++j) {
            svp += s[j] * Fs[p][j];
            A   += Ms[j][p] * GMs[j][p];
            B   += s[j] * Ms[j][p];
            bM  += b1[j] * Ms[j][p];
            bsum += b1[j];
        }
        sv[p] = svp;
        float Esum = (float)N_ROWS * bsum * (1.0f / 64.0f);   // sum_n e[n]
        float Su   = (float)N_ROWS * bM - Esum * svp;         // sum_n u[n,p]
        float Su2  = A - 2.0f * svp * B + E2[0] * svp * svp;  // sum_n u^2
        float f = fcb[p];
        float csum2 = Su + (float)N_ROWS * f;
        float csq2  = Su2 + 2.0f * f * Su + (float)N_ROWS * f * f;
        float m2 = csum2 * (1.0f / N_ROWS);
        float v2 = csq2 * (1.0f / N_ROWS) - m2 * m2;
        float a = bn2w[p] * rsqrtf(v2 + 1e-5f);
        a2[p] = a;
        c2[p] = bn2b[p] - m2 * a;
    }
}

// y[n] = sum_p lrelu((hbn[n,:]M[:,p] - e[n]sv[p] + fcb[p])*a2[p]+c2[p]) * wout[p] + bout
// 256 blocks x 256 thr; 32 rows/block; 8 threads/row, 8 p's each.
__global__ __launch_bounds__(256)
void final_kernel(const float* __restrict__ hidden, const float* __restrict__ colsum,
                  const float* __restrict__ colsumsq, const float* __restrict__ bnw,
                  const float* __restrict__ bnb, const float* __restrict__ M,
                  const float* __restrict__ sv, const float* __restrict__ fcb,
                  const float* __restrict__ a2, const float* __restrict__ c2,
                  const float* __restrict__ wout, const float* __restrict__ bout,
                  float* __restrict__ y)
{
    __shared__ float a1s[64], c1s[64];
    __shared__ float svs[64], fcs[64], a2s[64], c2s[64], ws[64];
    __shared__ float Ms[64][66];
    __shared__ float tile[32][65];
    __shared__ float el[32];
    const int b = blockIdx.x, tid = threadIdx.x;

    if (tid < 64) {
        float m = colsum[tid] * (1.0f / N_ROWS);
        float v = colsumsq[tid] * (1.0f / N_ROWS) - m * m;
        float a = bnw[tid] * rsqrtf(v + 1e-5f);
        a1s[tid] = a;
        c1s[tid] = bnb[tid] - m * a;
        svs[tid] = sv[tid];
        fcs[tid] = fcb[tid];
        a2s[tid] = a2[tid];
        c2s[tid] = c2[tid];
        ws[tid]  = wout[tid];
    }
    for (int i = tid; i < 4096; i += 256) Ms[i >> 6][i & 63] = M[i];
    __syncthreads();
    for (int i = tid; i < 32 * 64; i += 256) {
        int r = i >> 6, c = i & 63;
        tile[r][c] = hidden[(long)(b * 32 + r) * 64 + c] * a1s[c] + c1s[c];
    }
    __syncthreads();
    if (tid < 32) {
        float sum = 0.0f;
#pragma unroll 8
        for (int c = 0; c < 64; ++c) sum += tile[tid][c];
        el[tid] = sum * (1.0f / 64.0f);
    }
    __syncthreads();

    const int row = tid >> 3, pg = (tid & 7) << 3;
    float acc[8];
#pragma unroll
    for (int i = 0; i < 8; ++i) acc[i] = 0.0f;
#pragma unroll 8
    for (int k = 0; k < 64; ++k) {
        float hv = tile[row][k];
#pragma unroll
        for (int i = 0; i < 8; ++i) acc[i] += hv * Ms[k][pg + i];
    }
    const float ev = el[row];
    float part = 0.0f;
#pragma unroll
    for (int i = 0; i < 8; ++i) {
        int p = pg + i;
        float v = acc[i] - ev * svs[p] + fcs[p];
        v = v * a2s[p] + c2s[p];
        v = (v >= 0.0f) ? v : 0.01f * v;
        part += v * ws[p];
    }
    part += __shfl_xor(part, 1);
    part += __shfl_xor(part, 2);
    part += __shfl_xor(part, 4);
    if ((tid & 7) == 0)
        y[b * 32 + row] = part + bout[0];
}

extern "C" void kernel_launch(void* const* d_in, const int* in_sizes, int n_in,
                              void* d_out, int out_size, void* d_ws, size_t ws_size,
                              hipStream_t stream)
{
    const float* x    = (const float*)d_in[0];
    const float* Wih0 = (const float*)d_in[1];
    const float* Whh0 = (const float*)d_in[2];
    const float* bih0 = (const float*)d_in[3];
    const float* bhh0 = (const float*)d_in[4];
    const float* Wih1 = (const float*)d_in[5];
    const float* Whh1 = (const float*)d_in[6];
    const float* bih1 = (const float*)d_in[7];
    const float* bhh1 = (const float*)d_in[8];
    const float* bn1w = (const float*)d_in[9];
    const float* bn1b = (const float*)d_in[10];
    const float* fcw  = (const float*)d_in[11];
    const float* fcb  = (const float*)d_in[12];
    const float* bn2w = (const float*)d_in[13];
    const float* bn2b = (const float*)d_in[14];
    const float* fow  = (const float*)d_in[15];
    const float* fob  = (const float*)d_in[16];
    float* y = (float*)d_out;

    float* ws = (float*)d_ws;
    float* hidden  = ws;                 // 8192*64
    float* sm      = ws + 524288;
    float* colsum   = sm;                // 64    } zeroed
    float* colsumsq = sm + 64;           // 64    } zeroed
    float* G        = sm + 128;          // 4096  } zeroed
    float* s        = sm + 4224;         // 64    } zeroed
    float* E2       = sm + 4288;         // 16    } zeroed
    float* M        = sm + 4304;         // 4096
    float* sv       = sm + 8400;         // 64
    float* a2       = sm + 8464;         // 64
    float* c2       = sm + 8528;         // 64

    hipMemsetAsync(colsum, 0, 4304 * sizeof(float), stream);

    gru_fused<<<512, 256, 0, stream>>>(x, Wih0, Whh0, bih0, bhh0,
                                       Wih1, Whh1, bih1, bhh1,
                                       hidden, colsum, colsumsq);
    stats_kernel<<<64, 256, 0, stream>>>(hidden, colsum, colsumsq, bn1w, bn1b,
                                         G, s, E2);
    prep_kernel<<<1, 256, 0, stream>>>(G, s, E2, fcw, fcb, bn1b, bn2w, bn2b,
                                       M, sv, a2, c2);
    final_kernel<<<256, 256, 0, stream>>>(hidden, colsum, colsumsq, bn1w, bn1b,
                                          M, sv, fcb, a2, c2, fow, fob, y);
}